// Round 1
// baseline (892.412 us; speedup 1.0000x reference)
//
#include <hip/hip_runtime.h>
#include <math.h>

// CirculantAttention on MI355X.
// Identity used: irfft2(conj(F(a))*F(b)) = circular cross-correlation; the
// channel-mixing matmuls commute with the spatial FFT, so all GEMMs run in
// the spatial domain and only two FFT-correlation kernels are needed.
//   attn_logit[m] = N^{-1/2} * sum_t Xq[t] Xk[t+m]   (softmax over m per (b,c))
//   out[m]        =          sum_t attn[t] Xv[t+m]
// Layout is channel-major [b, c, n=h*128+w] end-to-end (output needs no transpose).

constexpr int CH    = 128;
constexpr int NSP   = 128 * 128;   // 16384 spatial positions
constexpr int BATCH = 8;
constexpr int NIMG  = BATCH * CH;  // 1024 images
constexpr int LROW  = 129;         // LDS row stride (pad +1: conflict-free column FFT)

// ---------------- wave-level 128-point FFT (2 complex per lane) ----------------

struct Tw { float wr[7]; float wi[7]; };

__device__ __forceinline__ void bfly(float& xr, float& xi, int s, float wr, float wi, int lane) {
  float pr = __shfl_xor(xr, s, 64);
  float pi = __shfl_xor(xi, s, 64);
  const bool bot = (lane & s) != 0;
  float tr = bot ? (pr - xr) : (xr + pr);
  float ti = bot ? (pi - xi) : (xi + pi);
  float cwr = bot ? wr : 1.0f;
  float cwi = bot ? wi : 0.0f;
  xr = tr * cwr - ti * cwi;
  xi = tr * cwi + ti * cwr;
}

// DIF radix-2: natural-order in, bit-reversed out. Lane l holds x[l], x[l+64].
__device__ __forceinline__ void fft128(float& v0r, float& v0i, float& v1r, float& v1i,
                                       const Tw& tw, int lane) {
  // stage span 64: both elements in-lane; twiddle W_128^lane applied to bottom
  float ur = v0r + v1r, ui = v0i + v1i;
  float dr = v0r - v1r, di = v0i - v1i;
  v0r = ur; v0i = ui;
  v1r = dr * tw.wr[0] - di * tw.wi[0];
  v1i = dr * tw.wi[0] + di * tw.wr[0];
  // spans 32..1 via shfl_xor; twiddle W_{2s}^{lane&(s-1)} on bottom lanes
#pragma unroll
  for (int k = 1; k < 7; ++k) {
    const int s = 64 >> k;
    bfly(v0r, v0i, s, tw.wr[k], tw.wi[k], lane);
    bfly(v1r, v1i, s, tw.wr[k], tw.wi[k], lane);
  }
}

// Full 2D forward FFT over the LDS image; bitrev-corrected writes give
// natural frequency order. Caller must have barriered before entry.
__device__ __forceinline__ void fft2d(float* re, float* im, const Tw& tw,
                                      int lane, int wid, int k0) {
  for (int r = wid; r < 128; r += 8) {
    const int base = r * LROW;
    float v0r = re[base + lane],      v0i = im[base + lane];
    float v1r = re[base + lane + 64], v1i = im[base + lane + 64];
    fft128(v0r, v0i, v1r, v1i, tw, lane);
    re[base + k0]     = v0r; im[base + k0]     = v0i;
    re[base + k0 + 1] = v1r; im[base + k0 + 1] = v1i;
  }
  __syncthreads();
  for (int c = wid; c < 128; c += 8) {
    float v0r = re[lane * LROW + c],        v0i = im[lane * LROW + c];
    float v1r = re[(lane + 64) * LROW + c], v1i = im[(lane + 64) * LROW + c];
    fft128(v0r, v0i, v1r, v1i, tw, lane);
    re[k0 * LROW + c]       = v0r; im[k0 * LROW + c]       = v0i;
    re[(k0 + 1) * LROW + c] = v1r; im[(k0 + 1) * LROW + c] = v1i;
  }
  __syncthreads();
}

// MODE 0: A=Xq, B=Xk -> softmax(N^{-3/2} * ifft_un(conj(FA)*FB)) -> Out
// MODE 1: A=attn, B=Xv -> N^{-1} * ifft_un(conj(FA)*FB) -> Out
template <int MODE>
__global__ __launch_bounds__(512)
void fft_corr_kernel(const float* __restrict__ Ain, const float* __restrict__ Bin,
                     float* __restrict__ Out) {
  __shared__ float re[128 * LROW];   // 66 KB
  __shared__ float im[128 * LROW];   // 66 KB  (total 132 KB < 160 KB/CU)
  __shared__ float tbl_r[64];
  __shared__ float tbl_i[64];
  __shared__ float red[16];
  const int tid  = threadIdx.x;
  const int lane = tid & 63;
  const int wid  = tid >> 6;
  const size_t off = (size_t)blockIdx.x * NSP;

  if (tid < 64) {
    float s, c;
    sincosf(6.283185307179586f * (float)tid * (1.0f / 128.0f), &s, &c);
    tbl_r[tid] = c; tbl_i[tid] = -s;           // W_128^k = e^{-2pi i k/128}
  }
  // pack z = A + i*B into LDS
#pragma unroll
  for (int i = 0; i < 8; ++i) {
    const int q = tid + i * 512;               // float4 id, 4096 total
    const int e = q * 4;
    const int r = e >> 7, cc = e & 127;
    const float4 a4 = *(const float4*)(Ain + off + e);
    const float4 b4 = *(const float4*)(Bin + off + e);
    const int base = r * LROW + cc;
    re[base + 0] = a4.x; re[base + 1] = a4.y; re[base + 2] = a4.z; re[base + 3] = a4.w;
    im[base + 0] = b4.x; im[base + 1] = b4.y; im[base + 2] = b4.z; im[base + 3] = b4.w;
  }
  __syncthreads();

  Tw tw;
  tw.wr[0] = tbl_r[lane]; tw.wi[0] = tbl_i[lane];
#pragma unroll
  for (int k = 1; k < 7; ++k) {
    const int s = 64 >> k;
    const int j = (lane & (s - 1)) * (64 / s);
    tw.wr[k] = tbl_r[j]; tw.wi[k] = tbl_i[j];
  }
  const int k0 = (int)(__brev((unsigned)lane) >> 25);  // bitrev7(lane), even

  fft2d(re, im, tw, lane, wid, k0);   // forward

  // Hermitian extraction + Y = conj(A_f)*B_f; write conj(Y) so that a second
  // forward FFT == unnormalized inverse (take real part).
  for (int idx = tid; idx < NSP; idx += 512) {
    const int fr = idx >> 7, fc = idx & 127;
    const int gr = (128 - fr) & 127, gc = (128 - fc) & 127;
    const int gidx = (gr << 7) | gc;
    if (idx > gidx) continue;
    const int af = fr * LROW + fc;
    const float zfr = re[af], zfi = im[af];
    if (idx == gidx) {                 // self-conjugate freq: A=Re(Z), B=Im(Z)
      re[af] = zfr * zfi;
      im[af] = 0.0f;
    } else {
      const int ag = gr * LROW + gc;
      const float zgr = re[ag], zgi = im[ag];
      const float qr = 0.5f * (zfr + zgr), qi = 0.5f * (zfi - zgi);   // A_f
      const float kr = 0.5f * (zfi + zgi), ki = 0.5f * (zgr - zfr);   // B_f
      const float yr = qr * kr + qi * ki;                             // conj(A)B
      const float yi = qr * ki - qi * kr;
      re[af] = yr; im[af] = -yi;       // conj(Y[f])
      re[ag] = yr; im[ag] = yi;        // conj(Y[g]) = conj(conj(Y[f])) = Y[f]
    }
  }
  __syncthreads();

  fft2d(re, im, tw, lane, wid, k0);   // == unnormalized inverse (real part)

  if (MODE == 0) {
    const float scale = 1.0f / 2097152.0f;   // N^{-3/2}, N=16384
    float m = -3.0e38f;
#pragma unroll 4
    for (int i = 0; i < 32; ++i) {
      const int e = tid + i * 512;
      m = fmaxf(m, re[(e >> 7) * LROW + (e & 127)]);
    }
#pragma unroll
    for (int s = 32; s >= 1; s >>= 1) m = fmaxf(m, __shfl_xor(m, s, 64));
    if (lane == 0) red[wid] = m;
    __syncthreads();
    m = red[0];
#pragma unroll
    for (int w = 1; w < 8; ++w) m = fmaxf(m, red[w]);
    float sum = 0.0f;
#pragma unroll 4
    for (int i = 0; i < 32; ++i) {
      const int e = tid + i * 512;
      sum += __expf((re[(e >> 7) * LROW + (e & 127)] - m) * scale);
    }
#pragma unroll
    for (int s = 32; s >= 1; s >>= 1) sum += __shfl_xor(sum, s, 64);
    if (lane == 0) red[8 + wid] = sum;
    __syncthreads();
    sum = 0.0f;
#pragma unroll
    for (int w = 0; w < 8; ++w) sum += red[8 + w];
    const float inv = 1.0f / sum;
#pragma unroll
    for (int i = 0; i < 8; ++i) {
      const int q = tid + i * 512;
      const int e = q * 4;
      const int base = (e >> 7) * LROW + (e & 127);
      float4 o;
      o.x = __expf((re[base + 0] - m) * scale) * inv;
      o.y = __expf((re[base + 1] - m) * scale) * inv;
      o.z = __expf((re[base + 2] - m) * scale) * inv;
      o.w = __expf((re[base + 3] - m) * scale) * inv;
      *(float4*)(Out + off + e) = o;
    }
  } else {
    const float scale = 1.0f / 16384.0f;     // 1/N
#pragma unroll
    for (int i = 0; i < 8; ++i) {
      const int q = tid + i * 512;
      const int e = q * 4;
      const int base = (e >> 7) * LROW + (e & 127);
      float4 o;
      o.x = re[base + 0] * scale;
      o.y = re[base + 1] * scale;
      o.z = re[base + 2] * scale;
      o.w = re[base + 3] * scale;
      *(float4*)(Out + off + e) = o;
    }
  }
}

// ---------------- GEMM 1: [Wqkv;Wgate](512x128) @ x(128xN) per batch ----------------
// out rows 0..127->Q, 128..255->K, 256..383->V, 384..511->silu(.+b_gate)->T

__global__ __launch_bounds__(256)
void gemm_qkvg(const float* __restrict__ x, const float* __restrict__ w_qkv,
               const float* __restrict__ w_gate, const float* __restrict__ b_gate,
               float* __restrict__ Q, float* __restrict__ K,
               float* __restrict__ V, float* __restrict__ T) {
  __shared__ float Xs[128 * 64];   // [k][n] 32 KB
  __shared__ float Ws[128 * 64];   // [k][d] (transposed) 32 KB
  const int tid = threadIdx.x;
  const int n0 = blockIdx.x * 64;
  const int d0 = blockIdx.y * 64;  // 0..448
  const int b  = blockIdx.z;

  const float* xb = x + (size_t)b * CH * NSP;
#pragma unroll
  for (int i = 0; i < 8; ++i) {
    const int q = tid + i * 256;             // 2048 float4
    const int k = q >> 4;
    const int c4 = (q & 15) * 4;
    const float4 v = *(const float4*)(xb + (size_t)k * NSP + n0 + c4);
    *(float4*)(&Xs[k * 64 + c4]) = v;
  }
  {
    const int dd = tid & 63;
    const int kk = (tid >> 6) * 32;
    const int d = d0 + dd;
    const float* wrow = (d < 384) ? (w_qkv + (size_t)d * CH)
                                  : (w_gate + (size_t)(d - 384) * CH);
#pragma unroll
    for (int j4 = 0; j4 < 8; ++j4) {
      const float4 wv = *(const float4*)(wrow + kk + j4 * 4);
      Ws[(kk + j4 * 4 + 0) * 64 + dd] = wv.x;
      Ws[(kk + j4 * 4 + 1) * 64 + dd] = wv.y;
      Ws[(kk + j4 * 4 + 2) * 64 + dd] = wv.z;
      Ws[(kk + j4 * 4 + 3) * 64 + dd] = wv.w;
    }
  }
  __syncthreads();

  const int tx = tid & 15, ty = tid >> 4;
  float acc[4][4] = {};
#pragma unroll 4
  for (int k = 0; k < 128; ++k) {
    float xv[4], wv[4];
    *(float4*)xv = *(const float4*)(&Xs[k * 64 + tx * 4]);
    *(float4*)wv = *(const float4*)(&Ws[k * 64 + ty * 4]);
#pragma unroll
    for (int i = 0; i < 4; ++i)
#pragma unroll
      for (int j = 0; j < 4; ++j)
        acc[i][j] = fmaf(wv[i], xv[j], acc[i][j]);
  }

  const int dsel = d0 >> 7;  // 0:Q 1:K 2:V 3:gate  (uniform per block)
  float* targ = (dsel == 0) ? Q : (dsel == 1) ? K : (dsel == 2) ? V : T;
  const int drel = d0 & 127;
#pragma unroll
  for (int i = 0; i < 4; ++i) {
    const int d = drel + ty * 4 + i;
    float vv[4];
    if (dsel == 3) {
      const float bg = b_gate[d];
#pragma unroll
      for (int j = 0; j < 4; ++j) {
        const float g = acc[i][j] + bg;
        vv[j] = g / (1.0f + __expf(-g));   // silu
      }
    } else {
#pragma unroll
      for (int j = 0; j < 4; ++j) vv[j] = acc[i][j];
    }
    *(float4*)(targ + ((size_t)b * CH + d) * NSP + n0 + tx * 4) = *(float4*)vv;
  }
}

// ---------------- GEMM 2: w_proj(128x128) @ (oc .* t)(128xN) + b_proj ----------------

__global__ __launch_bounds__(256)
void gemm_proj(const float* __restrict__ OC, const float* __restrict__ T,
               const float* __restrict__ w_proj, const float* __restrict__ b_proj,
               float* __restrict__ outp) {
  __shared__ float Xs[128 * 64];
  __shared__ float Ws[128 * 64];
  const int tid = threadIdx.x;
  const int n0 = blockIdx.x * 64;
  const int e0 = blockIdx.y * 64;
  const int b  = blockIdx.z;

#pragma unroll
  for (int i = 0; i < 8; ++i) {
    const int q = tid + i * 256;
    const int k = q >> 4;
    const int c4 = (q & 15) * 4;
    const size_t gi = ((size_t)b * CH + k) * NSP + n0 + c4;
    const float4 a = *(const float4*)(OC + gi);
    const float4 t = *(const float4*)(T + gi);
    float4 z;
    z.x = a.x * t.x; z.y = a.y * t.y; z.z = a.z * t.z; z.w = a.w * t.w;
    *(float4*)(&Xs[k * 64 + c4]) = z;
  }
  {
    const int ee = tid & 63;
    const int kk = (tid >> 6) * 32;
    const float* wrow = w_proj + (size_t)(e0 + ee) * CH;
#pragma unroll
    for (int j4 = 0; j4 < 8; ++j4) {
      const float4 wv = *(const float4*)(wrow + kk + j4 * 4);
      Ws[(kk + j4 * 4 + 0) * 64 + ee] = wv.x;
      Ws[(kk + j4 * 4 + 1) * 64 + ee] = wv.y;
      Ws[(kk + j4 * 4 + 2) * 64 + ee] = wv.z;
      Ws[(kk + j4 * 4 + 3) * 64 + ee] = wv.w;
    }
  }
  __syncthreads();

  const int tx = tid & 15, ty = tid >> 4;
  float acc[4][4] = {};
#pragma unroll 4
  for (int k = 0; k < 128; ++k) {
    float xv[4], wv[4];
    *(float4*)xv = *(const float4*)(&Xs[k * 64 + tx * 4]);
    *(float4*)wv = *(const float4*)(&Ws[k * 64 + ty * 4]);
#pragma unroll
    for (int i = 0; i < 4; ++i)
#pragma unroll
      for (int j = 0; j < 4; ++j)
        acc[i][j] = fmaf(wv[i], xv[j], acc[i][j]);
  }

#pragma unroll
  for (int i = 0; i < 4; ++i) {
    const int e = e0 + ty * 4 + i;
    const float bp = b_proj[e];
    float vv[4];
#pragma unroll
    for (int j = 0; j < 4; ++j) vv[j] = acc[i][j] + bp;
    *(float4*)(outp + ((size_t)b * CH + e) * NSP + n0 + tx * 4) = *(float4*)vv;
  }
}

// ---------------- launch ----------------

extern "C" void kernel_launch(void* const* d_in, const int* in_sizes, int n_in,
                              void* d_out, int out_size, void* d_ws, size_t ws_size,
                              hipStream_t stream) {
  const float* x      = (const float*)d_in[0];
  const float* w_qkv  = (const float*)d_in[1];
  const float* w_gate = (const float*)d_in[2];
  const float* b_gate = (const float*)d_in[3];
  const float* w_proj = (const float*)d_in[4];
  const float* b_proj = (const float*)d_in[5];
  float* outp = (float*)d_out;

  const size_t SZ = (size_t)BATCH * CH * NSP;  // 16,777,216 floats each
  float* Q = (float*)d_ws;       // later: attn, then out_corr (in-place per image)
  float* K = Q + SZ;
  float* V = K + SZ;
  float* T = V + SZ;             // total ws use: 256 MiB

  dim3 g1(NSP / 64, 8, BATCH);
  gemm_qkvg<<<g1, 256, 0, stream>>>(x, w_qkv, w_gate, b_gate, Q, K, V, T);

  fft_corr_kernel<0><<<NIMG, 512, 0, stream>>>(Q, K, Q);  // attn = softmax(corr(Q,K))
  fft_corr_kernel<1><<<NIMG, 512, 0, stream>>>(Q, V, Q);  // oc = corr(attn, V)

  dim3 g2(NSP / 64, 2, BATCH);
  gemm_proj<<<g2, 256, 0, stream>>>(Q, T, w_proj, b_proj, outp);
}

// Round 2
// 813.390 us; speedup vs baseline: 1.0972x; 1.0972x over previous
//
#include <hip/hip_runtime.h>
#include <math.h>

// CirculantAttention on MI355X.
//   attn = softmax_n( N^{-1/2} * circ_corr(Xq, Xk) )   per (b,c) image
//   out  = circ_corr(attn, Xv)
// All channel GEMMs in spatial domain (commute with FFT). One fused FFT kernel
// does corr -> softmax -> corr per image, attn never leaves LDS.

constexpr int CH    = 128;
constexpr int NSP   = 128 * 128;   // 16384
constexpr int BATCH = 8;
constexpr int NIMG  = BATCH * CH;  // 1024 images
constexpr int LROW  = 129;         // +1 pad: conflict-free column FFT
constexpr int NT    = 1024;        // threads per fft block (16 waves)
constexpr int NW    = NT / 64;

// ---------------- wave-level 128-pt FFT, hoisted twiddles, 2-FFT ILP ----------------

struct Tw {
  float w0r, w0i;          // W_128^lane, stage 0 (in-lane)
  float er[7], ei[7], sg[7];  // per-stage effective twiddle + butterfly sign (k=1..6)
};

__device__ __forceinline__ void bfly1(float& xr, float& xi, int s,
                                      float sg, float ewr, float ewi) {
  float pr = __shfl_xor(xr, s, 64);
  float pi = __shfl_xor(xi, s, 64);
  float tr = fmaf(sg, xr, pr);     // top: xr+pr, bottom: pr-xr
  float ti = fmaf(sg, xi, pi);
  xr = fmaf(tr, ewr, -ti * ewi);   // top lanes: ewr=1, ewi=0 -> passthrough
  xi = fmaf(tr, ewi, ti * ewr);
}

// Two independent 128-pt DIF FFTs (4 dependency chains/lane). Natural in,
// bit-reversed out (caller corrects with k0).
__device__ __forceinline__ void fft128_x2(
    float& a0r, float& a0i, float& a1r, float& a1i,
    float& b0r, float& b0i, float& b1r, float& b1i, const Tw& tw) {
  {
    float ur = a0r + a1r, ui = a0i + a1i;
    float dr = a0r - a1r, di = a0i - a1i;
    a0r = ur; a0i = ui;
    a1r = fmaf(dr, tw.w0r, -di * tw.w0i);
    a1i = fmaf(dr, tw.w0i,  di * tw.w0r);
    ur = b0r + b1r; ui = b0i + b1i;
    dr = b0r - b1r; di = b0i - b1i;
    b0r = ur; b0i = ui;
    b1r = fmaf(dr, tw.w0r, -di * tw.w0i);
    b1i = fmaf(dr, tw.w0i,  di * tw.w0r);
  }
#pragma unroll
  for (int k = 1; k < 7; ++k) {
    const int s = 64 >> k;
    bfly1(a0r, a0i, s, tw.sg[k], tw.er[k], tw.ei[k]);
    bfly1(b0r, b0i, s, tw.sg[k], tw.er[k], tw.ei[k]);
    bfly1(a1r, a1i, s, tw.sg[k], tw.er[k], tw.ei[k]);
    bfly1(b1r, b1i, s, tw.sg[k], tw.er[k], tw.ei[k]);
  }
}

// Full 2D FFT over the LDS image (rows then cols), natural frequency order out.
// Caller must have barriered before entry; exits barriered.
__device__ __forceinline__ void fft2d(float* re, float* im, const Tw& tw,
                                      int lane, int wid, int k0) {
#pragma unroll
  for (int it = 0; it < 4; ++it) {
    const int rA = (wid + it * 32) * LROW;
    const int rB = rA + 16 * LROW;
    float a0r = re[rA + lane],      a0i = im[rA + lane];
    float a1r = re[rA + lane + 64], a1i = im[rA + lane + 64];
    float b0r = re[rB + lane],      b0i = im[rB + lane];
    float b1r = re[rB + lane + 64], b1i = im[rB + lane + 64];
    fft128_x2(a0r, a0i, a1r, a1i, b0r, b0i, b1r, b1i, tw);
    re[rA + k0]     = a0r; im[rA + k0]     = a0i;
    re[rA + k0 + 1] = a1r; im[rA + k0 + 1] = a1i;
    re[rB + k0]     = b0r; im[rB + k0]     = b0i;
    re[rB + k0 + 1] = b1r; im[rB + k0 + 1] = b1i;
  }
  __syncthreads();
#pragma unroll
  for (int it = 0; it < 4; ++it) {
    const int cA = wid + it * 32;
    const int cB = cA + 16;
    float a0r = re[lane * LROW + cA],        a0i = im[lane * LROW + cA];
    float a1r = re[(lane + 64) * LROW + cA], a1i = im[(lane + 64) * LROW + cA];
    float b0r = re[lane * LROW + cB],        b0i = im[lane * LROW + cB];
    float b1r = re[(lane + 64) * LROW + cB], b1i = im[(lane + 64) * LROW + cB];
    fft128_x2(a0r, a0i, a1r, a1i, b0r, b0i, b1r, b1i, tw);
    re[k0 * LROW + cA]       = a0r; im[k0 * LROW + cA]       = a0i;
    re[(k0 + 1) * LROW + cA] = a1r; im[(k0 + 1) * LROW + cA] = a1i;
    re[k0 * LROW + cB]       = b0r; im[k0 * LROW + cB]       = b0i;
    re[(k0 + 1) * LROW + cB] = b1r; im[(k0 + 1) * LROW + cB] = b1i;
  }
  __syncthreads();
}

// Hermitian extraction of the two packed real spectra + Y = conj(A_f)*B_f,
// stored as conj(Y) so a second forward FFT == unnormalized inverse.
__device__ __forceinline__ void cross_spectrum(float* re, float* im, int tid) {
  for (int idx = tid; idx < NSP; idx += NT) {
    const int fr = idx >> 7, fc = idx & 127;
    const int gr = (128 - fr) & 127, gc = (128 - fc) & 127;
    const int gidx = (gr << 7) | gc;
    if (idx > gidx) continue;
    const int af = fr * LROW + fc;
    const float zfr = re[af], zfi = im[af];
    if (idx == gidx) {
      re[af] = zfr * zfi;
      im[af] = 0.0f;
    } else {
      const int ag = gr * LROW + gc;
      const float zgr = re[ag], zgi = im[ag];
      const float qr = 0.5f * (zfr + zgr), qi = 0.5f * (zfi - zgi);
      const float kr = 0.5f * (zfi + zgi), ki = 0.5f * (zgr - zfr);
      const float yr = qr * kr + qi * ki;
      const float yi = qr * ki - qi * kr;
      re[af] = yr; im[af] = -yi;
      re[ag] = yr; im[ag] = yi;
    }
  }
}

__global__ __launch_bounds__(NT)
void fft_attn_fused(const float* __restrict__ Qin, const float* __restrict__ Kin,
                    const float* __restrict__ Vin, float* __restrict__ Out) {
  __shared__ float re[128 * LROW];   // 66 KB
  __shared__ float im[128 * LROW];   // 66 KB
  __shared__ float tbl_r[64], tbl_i[64];
  __shared__ float red[2 * NW];
  const int tid  = threadIdx.x;
  const int lane = tid & 63;
  const int wid  = tid >> 6;
  const size_t off = (size_t)blockIdx.x * NSP;

  if (tid < 64) {
    float s, c;
    sincosf(6.283185307179586f * (float)tid * (1.0f / 128.0f), &s, &c);
    tbl_r[tid] = c; tbl_i[tid] = -s;     // W_128^k
  }
  // pack z = Q + i*K
#pragma unroll
  for (int i = 0; i < 4; ++i) {
    const int e = (tid + i * NT) * 4;
    const int base = (e >> 7) * LROW + (e & 127);
    const float4 a4 = *(const float4*)(Qin + off + e);
    const float4 b4 = *(const float4*)(Kin + off + e);
    re[base + 0] = a4.x; re[base + 1] = a4.y; re[base + 2] = a4.z; re[base + 3] = a4.w;
    im[base + 0] = b4.x; im[base + 1] = b4.y; im[base + 2] = b4.z; im[base + 3] = b4.w;
  }
  __syncthreads();

  Tw tw;
  tw.w0r = tbl_r[lane]; tw.w0i = tbl_i[lane];
#pragma unroll
  for (int k = 1; k < 7; ++k) {
    const int s = 64 >> k;
    const int j = (lane & (s - 1)) * (64 / s);
    const bool bot = (lane & s) != 0;
    tw.er[k] = bot ? tbl_r[j] : 1.0f;
    tw.ei[k] = bot ? tbl_i[j] : 0.0f;
    tw.sg[k] = bot ? -1.0f : 1.0f;
  }
  const int k0 = (int)(__brev((unsigned)lane) >> 25);  // bitrev7(lane), even

  // ---- stage 1: corr(Q,K) ----
  fft2d(re, im, tw, lane, wid, k0);
  cross_spectrum(re, im, tid);
  __syncthreads();
  fft2d(re, im, tw, lane, wid, k0);    // logits (unnormalized) in re

  // ---- softmax over the 16384 logits (scale folded into exp arg) ----
  const float scale = 1.0f / 2097152.0f;   // N^{-3/2}
  float m = -3.0e38f;
#pragma unroll
  for (int i = 0; i < 16; ++i) {
    const int e = tid + i * NT;
    m = fmaxf(m, re[(e >> 7) * LROW + (e & 127)]);
  }
#pragma unroll
  for (int s = 32; s >= 1; s >>= 1) m = fmaxf(m, __shfl_xor(m, s, 64));
  if (lane == 0) red[wid] = m;
  __syncthreads();
  m = red[0];
#pragma unroll
  for (int w = 1; w < NW; ++w) m = fmaxf(m, red[w]);
  float sum = 0.0f;
#pragma unroll
  for (int i = 0; i < 16; ++i) {
    const int e = tid + i * NT;
    const int a = (e >> 7) * LROW + (e & 127);
    const float ex = __expf((re[a] - m) * scale);
    im[a] = ex;                        // im plane is dead post-IFFT: use as scratch
    sum += ex;
  }
#pragma unroll
  for (int s = 32; s >= 1; s >>= 1) sum += __shfl_xor(sum, s, 64);
  if (lane == 0) red[NW + wid] = sum;
  __syncthreads();
  float tot = 0.0f;
#pragma unroll
  for (int w = 0; w < NW; ++w) tot += red[NW + w];
  const float inv = 1.0f / tot;
#pragma unroll
  for (int i = 0; i < 16; ++i) {
    const int e = tid + i * NT;
    const int a = (e >> 7) * LROW + (e & 127);
    re[a] = im[a] * inv;               // normalized attn, natural layout
  }
  __syncthreads();

  // ---- stage 2: corr(attn, V) ----
#pragma unroll
  for (int i = 0; i < 4; ++i) {
    const int e = (tid + i * NT) * 4;
    const int base = (e >> 7) * LROW + (e & 127);
    const float4 v4 = *(const float4*)(Vin + off + e);
    im[base + 0] = v4.x; im[base + 1] = v4.y; im[base + 2] = v4.z; im[base + 3] = v4.w;
  }
  __syncthreads();
  fft2d(re, im, tw, lane, wid, k0);
  cross_spectrum(re, im, tid);
  __syncthreads();
  fft2d(re, im, tw, lane, wid, k0);

  const float oscale = 1.0f / 16384.0f;  // 1/N
#pragma unroll
  for (int i = 0; i < 4; ++i) {
    const int e = (tid + i * NT) * 4;
    const int base = (e >> 7) * LROW + (e & 127);
    float4 o;
    o.x = re[base + 0] * oscale;
    o.y = re[base + 1] * oscale;
    o.z = re[base + 2] * oscale;
    o.w = re[base + 3] * oscale;
    *(float4*)(Out + off + e) = o;
  }
}

// ---------------- GEMM 1: [Wqkv;Wgate](512x128) @ x(128xN) per batch ----------------

__global__ __launch_bounds__(256)
void gemm_qkvg(const float* __restrict__ x, const float* __restrict__ w_qkv,
               const float* __restrict__ w_gate, const float* __restrict__ b_gate,
               float* __restrict__ Q, float* __restrict__ K,
               float* __restrict__ V, float* __restrict__ T) {
  __shared__ float Xs[128 * 64];
  __shared__ float Ws[128 * 64];
  const int tid = threadIdx.x;
  const int n0 = blockIdx.x * 64;
  const int d0 = blockIdx.y * 64;
  const int b  = blockIdx.z;

  const float* xb = x + (size_t)b * CH * NSP;
#pragma unroll
  for (int i = 0; i < 8; ++i) {
    const int q = tid + i * 256;
    const int k = q >> 4;
    const int c4 = (q & 15) * 4;
    const float4 v = *(const float4*)(xb + (size_t)k * NSP + n0 + c4);
    *(float4*)(&Xs[k * 64 + c4]) = v;
  }
  {
    const int dd = tid & 63;
    const int kk = (tid >> 6) * 32;
    const int d = d0 + dd;
    const float* wrow = (d < 384) ? (w_qkv + (size_t)d * CH)
                                  : (w_gate + (size_t)(d - 384) * CH);
#pragma unroll
    for (int j4 = 0; j4 < 8; ++j4) {
      const float4 wv = *(const float4*)(wrow + kk + j4 * 4);
      Ws[(kk + j4 * 4 + 0) * 64 + dd] = wv.x;
      Ws[(kk + j4 * 4 + 1) * 64 + dd] = wv.y;
      Ws[(kk + j4 * 4 + 2) * 64 + dd] = wv.z;
      Ws[(kk + j4 * 4 + 3) * 64 + dd] = wv.w;
    }
  }
  __syncthreads();

  const int tx = tid & 15, ty = tid >> 4;
  float acc[4][4] = {};
#pragma unroll 4
  for (int k = 0; k < 128; ++k) {
    float xv[4], wv[4];
    *(float4*)xv = *(const float4*)(&Xs[k * 64 + tx * 4]);
    *(float4*)wv = *(const float4*)(&Ws[k * 64 + ty * 4]);
#pragma unroll
    for (int i = 0; i < 4; ++i)
#pragma unroll
      for (int j = 0; j < 4; ++j)
        acc[i][j] = fmaf(wv[i], xv[j], acc[i][j]);
  }

  const int dsel = d0 >> 7;
  float* targ = (dsel == 0) ? Q : (dsel == 1) ? K : (dsel == 2) ? V : T;
  const int drel = d0 & 127;
#pragma unroll
  for (int i = 0; i < 4; ++i) {
    const int d = drel + ty * 4 + i;
    float vv[4];
    if (dsel == 3) {
      const float bg = b_gate[d];
#pragma unroll
      for (int j = 0; j < 4; ++j) {
        const float g = acc[i][j] + bg;
        vv[j] = g / (1.0f + __expf(-g));
      }
    } else {
#pragma unroll
      for (int j = 0; j < 4; ++j) vv[j] = acc[i][j];
    }
    *(float4*)(targ + ((size_t)b * CH + d) * NSP + n0 + tx * 4) = *(float4*)vv;
  }
}

// ---------------- GEMM 2: w_proj @ (oc .* t) + b_proj ----------------

__global__ __launch_bounds__(256)
void gemm_proj(const float* __restrict__ OC, const float* __restrict__ T,
               const float* __restrict__ w_proj, const float* __restrict__ b_proj,
               float* __restrict__ outp) {
  __shared__ float Xs[128 * 64];
  __shared__ float Ws[128 * 64];
  const int tid = threadIdx.x;
  const int n0 = blockIdx.x * 64;
  const int e0 = blockIdx.y * 64;
  const int b  = blockIdx.z;

#pragma unroll
  for (int i = 0; i < 8; ++i) {
    const int q = tid + i * 256;
    const int k = q >> 4;
    const int c4 = (q & 15) * 4;
    const size_t gi = ((size_t)b * CH + k) * NSP + n0 + c4;
    const float4 a = *(const float4*)(OC + gi);
    const float4 t = *(const float4*)(T + gi);
    float4 z;
    z.x = a.x * t.x; z.y = a.y * t.y; z.z = a.z * t.z; z.w = a.w * t.w;
    *(float4*)(&Xs[k * 64 + c4]) = z;
  }
  {
    const int ee = tid & 63;
    const int kk = (tid >> 6) * 32;
    const float* wrow = w_proj + (size_t)(e0 + ee) * CH;
#pragma unroll
    for (int j4 = 0; j4 < 8; ++j4) {
      const float4 wv = *(const float4*)(wrow + kk + j4 * 4);
      Ws[(kk + j4 * 4 + 0) * 64 + ee] = wv.x;
      Ws[(kk + j4 * 4 + 1) * 64 + ee] = wv.y;
      Ws[(kk + j4 * 4 + 2) * 64 + ee] = wv.z;
      Ws[(kk + j4 * 4 + 3) * 64 + ee] = wv.w;
    }
  }
  __syncthreads();

  const int tx = tid & 15, ty = tid >> 4;
  float acc[4][4] = {};
#pragma unroll 4
  for (int k = 0; k < 128; ++k) {
    float xv[4], wv[4];
    *(float4*)xv = *(const float4*)(&Xs[k * 64 + tx * 4]);
    *(float4*)wv = *(const float4*)(&Ws[k * 64 + ty * 4]);
#pragma unroll
    for (int i = 0; i < 4; ++i)
#pragma unroll
      for (int j = 0; j < 4; ++j)
        acc[i][j] = fmaf(wv[i], xv[j], acc[i][j]);
  }

#pragma unroll
  for (int i = 0; i < 4; ++i) {
    const int e = e0 + ty * 4 + i;
    const float bp = b_proj[e];
    float vv[4];
#pragma unroll
    for (int j = 0; j < 4; ++j) vv[j] = acc[i][j] + bp;
    *(float4*)(outp + ((size_t)b * CH + e) * NSP + n0 + tx * 4) = *(float4*)vv;
  }
}

// ---------------- launch ----------------

extern "C" void kernel_launch(void* const* d_in, const int* in_sizes, int n_in,
                              void* d_out, int out_size, void* d_ws, size_t ws_size,
                              hipStream_t stream) {
  const float* x      = (const float*)d_in[0];
  const float* w_qkv  = (const float*)d_in[1];
  const float* w_gate = (const float*)d_in[2];
  const float* b_gate = (const float*)d_in[3];
  const float* w_proj = (const float*)d_in[4];
  const float* b_proj = (const float*)d_in[5];
  float* outp = (float*)d_out;

  const size_t SZ = (size_t)BATCH * CH * NSP;
  float* Q = (float*)d_ws;   // also receives corr(attn,V) in-place
  float* K = Q + SZ;
  float* V = K + SZ;
  float* T = V + SZ;

  dim3 g1(NSP / 64, 8, BATCH);
  gemm_qkvg<<<g1, 256, 0, stream>>>(x, w_qkv, w_gate, b_gate, Q, K, V, T);

  fft_attn_fused<<<NIMG, NT, 0, stream>>>(Q, K, V, Q);

  dim3 g2(NSP / 64, 2, BATCH);
  gemm_proj<<<g2, 256, 0, stream>>>(Q, T, w_proj, b_proj, outp);
}

// Round 3
// 606.693 us; speedup vs baseline: 1.4709x; 1.3407x over previous
//
#include <hip/hip_runtime.h>
#include <math.h>

// CirculantAttention on MI355X.
//   attn = softmax_n( N^{-3/2} * circ_corr(Xq, Xk) )   per (b,c) image
//   out  = (1/N)    *  circ_corr(attn, Xv)             (fft-based, conj trick)
// FFT engine: 128 = 8x16 two-phase in-register FFT (radix-8 in regs, in-place
// LDS exchange, radix-16 in regs). No cross-lane shuffles: the LDS pipe only
// carries the unavoidable data movement (~1024 b64 ops per image pass, all
// access patterns exactly 4 lanes/bank = the b64 hardware floor).

constexpr int CH    = 128;
constexpr int NSP   = 128 * 128;   // 16384
constexpr int BATCH = 8;
constexpr int NIMG  = BATCH * CH;  // 1024
constexpr int RS    = 130;         // complex row stride (bank-optimal, b64)
constexpr int NT    = 1024;        // 16 waves
constexpr int NW    = NT / 64;

__device__ __forceinline__ float2 cmul(float2 a, float2 b) {
  return make_float2(fmaf(a.x, b.x, -(a.y * b.y)), fmaf(a.x, b.y, a.y * b.x));
}
#define CADD(a,b) make_float2((a).x+(b).x,(a).y+(b).y)
#define CSUB(a,b) make_float2((a).x-(b).x,(a).y-(b).y)
#define MULNI(t)  make_float2((t).y, -(t).x)      /* t * (-i) */
constexpr float C45 = 0.7071067811865476f;

// ---- FFT-8, DIF, in-register. Output: reg m holds X[br3(m)], br3={0,4,2,6,1,5,3,7}
__device__ __forceinline__ void fft8(float2* x) {
  float2 t;
  t = CSUB(x[0],x[4]); x[0]=CADD(x[0],x[4]); x[4]=t;
  t = CSUB(x[1],x[5]); x[1]=CADD(x[1],x[5]); x[5]=make_float2(C45*(t.x+t.y), C45*(t.y-t.x));
  t = CSUB(x[2],x[6]); x[2]=CADD(x[2],x[6]); x[6]=MULNI(t);
  t = CSUB(x[3],x[7]); x[3]=CADD(x[3],x[7]); x[7]=make_float2(C45*(t.y-t.x), -C45*(t.x+t.y));
  t = CSUB(x[0],x[2]); x[0]=CADD(x[0],x[2]); x[2]=t;
  t = CSUB(x[1],x[3]); x[1]=CADD(x[1],x[3]); x[3]=MULNI(t);
  t = CSUB(x[4],x[6]); x[4]=CADD(x[4],x[6]); x[6]=t;
  t = CSUB(x[5],x[7]); x[5]=CADD(x[5],x[7]); x[7]=MULNI(t);
  t = CSUB(x[0],x[1]); x[0]=CADD(x[0],x[1]); x[1]=t;
  t = CSUB(x[2],x[3]); x[2]=CADD(x[2],x[3]); x[3]=t;
  t = CSUB(x[4],x[5]); x[4]=CADD(x[4],x[5]); x[5]=t;
  t = CSUB(x[6],x[7]); x[6]=CADD(x[6],x[7]); x[7]=t;
}

// ---- FFT-16, DIF, in-register. Output: reg m holds X[br4(m)]
__device__ __forceinline__ void fft16(float2* z) {
  float2 t;
  // stage 1 span 8, twiddles W16^j
  t=CSUB(z[0],z[8]);   z[0]=CADD(z[0],z[8]);   z[8]=t;
  t=CSUB(z[1],z[9]);   z[1]=CADD(z[1],z[9]);   z[9]=cmul(t,  make_float2( 0.9238795325f,-0.3826834324f));
  t=CSUB(z[2],z[10]);  z[2]=CADD(z[2],z[10]);  z[10]=make_float2(C45*(t.x+t.y), C45*(t.y-t.x));
  t=CSUB(z[3],z[11]);  z[3]=CADD(z[3],z[11]);  z[11]=cmul(t, make_float2( 0.3826834324f,-0.9238795325f));
  t=CSUB(z[4],z[12]);  z[4]=CADD(z[4],z[12]);  z[12]=MULNI(t);
  t=CSUB(z[5],z[13]);  z[5]=CADD(z[5],z[13]);  z[13]=cmul(t, make_float2(-0.3826834324f,-0.9238795325f));
  t=CSUB(z[6],z[14]);  z[6]=CADD(z[6],z[14]);  z[14]=make_float2(C45*(t.y-t.x), -C45*(t.x+t.y));
  t=CSUB(z[7],z[15]);  z[7]=CADD(z[7],z[15]);  z[15]=cmul(t, make_float2(-0.9238795325f,-0.3826834324f));
  // stage 2 span 4, twiddles W8^j per 8-group
  t=CSUB(z[0],z[4]);   z[0]=CADD(z[0],z[4]);   z[4]=t;
  t=CSUB(z[1],z[5]);   z[1]=CADD(z[1],z[5]);   z[5]=make_float2(C45*(t.x+t.y), C45*(t.y-t.x));
  t=CSUB(z[2],z[6]);   z[2]=CADD(z[2],z[6]);   z[6]=MULNI(t);
  t=CSUB(z[3],z[7]);   z[3]=CADD(z[3],z[7]);   z[7]=make_float2(C45*(t.y-t.x), -C45*(t.x+t.y));
  t=CSUB(z[8],z[12]);  z[8]=CADD(z[8],z[12]);  z[12]=t;
  t=CSUB(z[9],z[13]);  z[9]=CADD(z[9],z[13]);  z[13]=make_float2(C45*(t.x+t.y), C45*(t.y-t.x));
  t=CSUB(z[10],z[14]); z[10]=CADD(z[10],z[14]); z[14]=MULNI(t);
  t=CSUB(z[11],z[15]); z[11]=CADD(z[11],z[15]); z[15]=make_float2(C45*(t.y-t.x), -C45*(t.x+t.y));
  // stage 3 span 2, twiddles 1, -i
  t=CSUB(z[0],z[2]);   z[0]=CADD(z[0],z[2]);   z[2]=t;
  t=CSUB(z[1],z[3]);   z[1]=CADD(z[1],z[3]);   z[3]=MULNI(t);
  t=CSUB(z[4],z[6]);   z[4]=CADD(z[4],z[6]);   z[6]=t;
  t=CSUB(z[5],z[7]);   z[5]=CADD(z[5],z[7]);   z[7]=MULNI(t);
  t=CSUB(z[8],z[10]);  z[8]=CADD(z[8],z[10]);  z[10]=t;
  t=CSUB(z[9],z[11]);  z[9]=CADD(z[9],z[11]);  z[11]=MULNI(t);
  t=CSUB(z[12],z[14]); z[12]=CADD(z[12],z[14]); z[14]=t;
  t=CSUB(z[13],z[15]); z[13]=CADD(z[13],z[15]); z[15]=MULNI(t);
  // stage 4 span 1
  t=CSUB(z[0],z[1]);   z[0]=CADD(z[0],z[1]);   z[1]=t;
  t=CSUB(z[2],z[3]);   z[2]=CADD(z[2],z[3]);   z[3]=t;
  t=CSUB(z[4],z[5]);   z[4]=CADD(z[4],z[5]);   z[5]=t;
  t=CSUB(z[6],z[7]);   z[6]=CADD(z[6],z[7]);   z[7]=t;
  t=CSUB(z[8],z[9]);   z[8]=CADD(z[8],z[9]);   z[9]=t;
  t=CSUB(z[10],z[11]); z[10]=CADD(z[10],z[11]); z[11]=t;
  t=CSUB(z[12],z[13]); z[12]=CADD(z[12],z[13]); z[13]=t;
  t=CSUB(z[14],z[15]); z[14]=CADD(z[14],z[15]); z[15]=t;
}

// One pass of 128 length-128 FFTs along dimension with stride SPT (point) /
// SLN (line). X[k] = sum x[16n1+n2] W128^{(16n1+n2)k}, k = k1 + 8 k2:
//   phase 1 (lane = 4 lines x n2in[0,16)): FFT8 over n1, twiddle W128^{n2 k1},
//     store in-place at cell 16 k1 + (n2 ^ k1)   (bank-minimal swizzle)
//   phase 2 (lane = 8 lines x k1in[0,8)): FFT16 over n2, store X natural order.
// Each wave owns lines [8*wid, 8*wid+8): no barrier inside the pass.
template<int SPT, int SLN>
__device__ __forceinline__ void fft_pass(float2* img, const float2* tw,
                                         int lane, int wid) {
  const int n2 = lane & 15, rr = lane >> 4;
  constexpr int br3[8] = {0,4,2,6,1,5,3,7};
#pragma unroll
  for (int u = 0; u < 2; ++u) {
    const int lb = SLN * (wid * 8 + u * 4 + rr);
    float2 x[8];
#pragma unroll
    for (int n1 = 0; n1 < 8; ++n1) x[n1] = img[lb + SPT * (16 * n1 + n2)];
    fft8(x);
#pragma unroll
    for (int m = 0; m < 8; ++m) {
      const int k1 = br3[m];
      const float2 y = (k1 == 0) ? x[m] : cmul(x[m], tw[k1 - 1]);
      img[lb + SPT * (16 * k1 + (n2 ^ k1))] = y;
    }
  }
  const int k1 = lane & 7;
  const int lb = SLN * (wid * 8 + (lane >> 3));
  const int kb = 16 * k1;
  float2 z[16];
#pragma unroll
  for (int j = 0; j < 16; ++j) z[j] = img[lb + SPT * (kb + (j ^ k1))];
  fft16(z);
  constexpr int br4[16] = {0,8,4,12,2,10,6,14,1,9,5,13,3,11,7,15};
#pragma unroll
  for (int m = 0; m < 16; ++m) img[lb + SPT * (k1 + 8 * br4[m])] = z[m];
}

__device__ __forceinline__ void fft2d(float2* img, const float2* tw,
                                      int lane, int wid) {
  fft_pass<1, RS>(img, tw, lane, wid);    // rows
  __syncthreads();
  fft_pass<RS, 1>(img, tw, lane, wid);    // cols
  __syncthreads();
}

// Hermitian split of packed spectra + Y = conj(A_f)*B_f, stored conj(Y) so a
// second forward FFT == unnormalized inverse (real part).
__device__ __forceinline__ void cross_spectrum(float2* img, int tid) {
  for (int idx = tid; idx < NSP; idx += NT) {
    const int fr = idx >> 7, fc = idx & 127;
    const int gr = (128 - fr) & 127, gc = (128 - fc) & 127;
    const int gidx = (gr << 7) | gc;
    if (idx > gidx) continue;
    const int f = fr * RS + fc;
    const float2 zf = img[f];
    if (idx == gidx) {
      img[f] = make_float2(zf.x * zf.y, 0.0f);
    } else {
      const int g = gr * RS + gc;
      const float2 zg = img[g];
      const float qr = 0.5f * (zf.x + zg.x), qi = 0.5f * (zf.y - zg.y);
      const float kr = 0.5f * (zf.y + zg.y), ki = 0.5f * (zg.x - zf.x);
      const float yr = qr * kr + qi * ki;
      const float yi = qr * ki - qi * kr;
      img[f] = make_float2(yr, -yi);
      img[g] = make_float2(yr, yi);
    }
  }
}

__global__ __launch_bounds__(NT)
void fft_attn_fused(const float* __restrict__ Qin, const float* __restrict__ Kin,
                    const float* __restrict__ Vin, float* __restrict__ Out) {
  __shared__ float2 img[128 * RS];   // 133,120 B
  __shared__ float red[2 * NW];
  const int tid = threadIdx.x, lane = tid & 63, wid = tid >> 6;
  const size_t off = (size_t)blockIdx.x * NSP;

  // per-lane phase-1 twiddles W128^{n2*k1}, shared by all 8 passes
  float2 tw[7];
  {
    const int n2 = lane & 15;
#pragma unroll
    for (int k = 1; k < 8; ++k) {
      float s, c;
      sincosf(6.283185307179586f * (float)(n2 * k) * (1.0f / 128.0f), &s, &c);
      tw[k - 1] = make_float2(c, -s);
    }
  }

  // pack z = Q + i*K
#pragma unroll
  for (int i = 0; i < 4; ++i) {
    const int e = (tid + i * NT) * 4;
    const float4 q4 = *(const float4*)(Qin + off + e);
    const float4 k4 = *(const float4*)(Kin + off + e);
    float2* p = img + (e >> 7) * RS + (e & 127);
    p[0] = make_float2(q4.x, k4.x); p[1] = make_float2(q4.y, k4.y);
    p[2] = make_float2(q4.z, k4.z); p[3] = make_float2(q4.w, k4.w);
  }
  __syncthreads();

  // ---- stage 1: corr(Q,K) ----
  fft2d(img, tw, lane, wid);
  cross_spectrum(img, tid);
  __syncthreads();
  fft2d(img, tw, lane, wid);     // unnormalized inverse: logits in .x

  // ---- softmax over 16384 logits ----
  const float scale = 1.0f / 2097152.0f;   // N^{-3/2}
  float m = -3.0e38f;
#pragma unroll
  for (int i = 0; i < 16; ++i) {
    const int e = tid + i * NT;
    m = fmaxf(m, img[(e >> 7) * RS + (e & 127)].x);
  }
#pragma unroll
  for (int s = 32; s >= 1; s >>= 1) m = fmaxf(m, __shfl_xor(m, s, 64));
  if (lane == 0) red[wid] = m;
  __syncthreads();
  m = red[0];
#pragma unroll
  for (int w = 1; w < NW; ++w) m = fmaxf(m, red[w]);
  float sum = 0.0f;
#pragma unroll
  for (int i = 0; i < 16; ++i) {
    const int e = tid + i * NT;
    float2* p = img + (e >> 7) * RS + (e & 127);
    const float ex = __expf((p->x - m) * scale);
    p->x = ex;
    sum += ex;
  }
#pragma unroll
  for (int s = 32; s >= 1; s >>= 1) sum += __shfl_xor(sum, s, 64);
  if (lane == 0) red[NW + wid] = sum;
  __syncthreads();
  float tot = 0.0f;
#pragma unroll
  for (int w = 0; w < NW; ++w) tot += red[NW + w];
  const float inv = 1.0f / tot;

  // normalize + pack z = attn + i*V  (barrier above orders exp stores)
#pragma unroll
  for (int i = 0; i < 4; ++i) {
    const int e = (tid + i * NT) * 4;
    const float4 v4 = *(const float4*)(Vin + off + e);
    float2* p = img + (e >> 7) * RS + (e & 127);
    p[0] = make_float2(p[0].x * inv, v4.x);
    p[1] = make_float2(p[1].x * inv, v4.y);
    p[2] = make_float2(p[2].x * inv, v4.z);
    p[3] = make_float2(p[3].x * inv, v4.w);
  }
  __syncthreads();

  // ---- stage 2: corr(attn, V) ----
  fft2d(img, tw, lane, wid);
  cross_spectrum(img, tid);
  __syncthreads();
  fft2d(img, tw, lane, wid);

  const float os = 1.0f / 16384.0f;   // 1/N
#pragma unroll
  for (int i = 0; i < 4; ++i) {
    const int e = (tid + i * NT) * 4;
    float2* p = img + (e >> 7) * RS + (e & 127);
    float4 o;
    o.x = p[0].x * os; o.y = p[1].x * os; o.z = p[2].x * os; o.w = p[3].x * os;
    *(float4*)(Out + off + e) = o;
  }
}

// ---------------- GEMM 1: [Wqkv;Wgate](512x128) @ x(128xN) per batch ----------------

__global__ __launch_bounds__(256)
void gemm_qkvg(const float* __restrict__ x, const float* __restrict__ w_qkv,
               const float* __restrict__ w_gate, const float* __restrict__ b_gate,
               float* __restrict__ Q, float* __restrict__ K,
               float* __restrict__ V, float* __restrict__ T) {
  __shared__ float Xs[128 * 64];
  __shared__ float Ws[128 * 64];
  const int tid = threadIdx.x;
  const int n0 = blockIdx.x * 64;
  const int d0 = blockIdx.y * 64;
  const int b  = blockIdx.z;

  const float* xb = x + (size_t)b * CH * NSP;
#pragma unroll
  for (int i = 0; i < 8; ++i) {
    const int q = tid + i * 256;
    const int k = q >> 4;
    const int c4 = (q & 15) * 4;
    const float4 v = *(const float4*)(xb + (size_t)k * NSP + n0 + c4);
    *(float4*)(&Xs[k * 64 + c4]) = v;
  }
  {
    const int dd = tid & 63;
    const int kk = (tid >> 6) * 32;
    const int d = d0 + dd;
    const float* wrow = (d < 384) ? (w_qkv + (size_t)d * CH)
                                  : (w_gate + (size_t)(d - 384) * CH);
#pragma unroll
    for (int j4 = 0; j4 < 8; ++j4) {
      const float4 wv = *(const float4*)(wrow + kk + j4 * 4);
      Ws[(kk + j4 * 4 + 0) * 64 + dd] = wv.x;
      Ws[(kk + j4 * 4 + 1) * 64 + dd] = wv.y;
      Ws[(kk + j4 * 4 + 2) * 64 + dd] = wv.z;
      Ws[(kk + j4 * 4 + 3) * 64 + dd] = wv.w;
    }
  }
  __syncthreads();

  const int tx = tid & 15, ty = tid >> 4;
  float acc[4][4] = {};
#pragma unroll 4
  for (int k = 0; k < 128; ++k) {
    float xv[4], wv[4];
    *(float4*)xv = *(const float4*)(&Xs[k * 64 + tx * 4]);
    *(float4*)wv = *(const float4*)(&Ws[k * 64 + ty * 4]);
#pragma unroll
    for (int i = 0; i < 4; ++i)
#pragma unroll
      for (int j = 0; j < 4; ++j)
        acc[i][j] = fmaf(wv[i], xv[j], acc[i][j]);
  }

  const int dsel = d0 >> 7;
  float* targ = (dsel == 0) ? Q : (dsel == 1) ? K : (dsel == 2) ? V : T;
  const int drel = d0 & 127;
#pragma unroll
  for (int i = 0; i < 4; ++i) {
    const int d = drel + ty * 4 + i;
    float vv[4];
    if (dsel == 3) {
      const float bg = b_gate[d];
#pragma unroll
      for (int j = 0; j < 4; ++j) {
        const float g = acc[i][j] + bg;
        vv[j] = g / (1.0f + __expf(-g));
      }
    } else {
#pragma unroll
      for (int j = 0; j < 4; ++j) vv[j] = acc[i][j];
    }
    *(float4*)(targ + ((size_t)b * CH + d) * NSP + n0 + tx * 4) = *(float4*)vv;
  }
}

// ---------------- GEMM 2: w_proj @ (oc .* t) + b_proj ----------------

__global__ __launch_bounds__(256)
void gemm_proj(const float* __restrict__ OC, const float* __restrict__ T,
               const float* __restrict__ w_proj, const float* __restrict__ b_proj,
               float* __restrict__ outp) {
  __shared__ float Xs[128 * 64];
  __shared__ float Ws[128 * 64];
  const int tid = threadIdx.x;
  const int n0 = blockIdx.x * 64;
  const int e0 = blockIdx.y * 64;
  const int b  = blockIdx.z;

#pragma unroll
  for (int i = 0; i < 8; ++i) {
    const int q = tid + i * 256;
    const int k = q >> 4;
    const int c4 = (q & 15) * 4;
    const size_t gi = ((size_t)b * CH + k) * NSP + n0 + c4;
    const float4 a = *(const float4*)(OC + gi);
    const float4 t = *(const float4*)(T + gi);
    float4 z;
    z.x = a.x * t.x; z.y = a.y * t.y; z.z = a.z * t.z; z.w = a.w * t.w;
    *(float4*)(&Xs[k * 64 + c4]) = z;
  }
  {
    const int ee = tid & 63;
    const int kk = (tid >> 6) * 32;
    const float* wrow = w_proj + (size_t)(e0 + ee) * CH;
#pragma unroll
    for (int j4 = 0; j4 < 8; ++j4) {
      const float4 wv = *(const float4*)(wrow + kk + j4 * 4);
      Ws[(kk + j4 * 4 + 0) * 64 + ee] = wv.x;
      Ws[(kk + j4 * 4 + 1) * 64 + ee] = wv.y;
      Ws[(kk + j4 * 4 + 2) * 64 + ee] = wv.z;
      Ws[(kk + j4 * 4 + 3) * 64 + ee] = wv.w;
    }
  }
  __syncthreads();

  const int tx = tid & 15, ty = tid >> 4;
  float acc[4][4] = {};
#pragma unroll 4
  for (int k = 0; k < 128; ++k) {
    float xv[4], wv[4];
    *(float4*)xv = *(const float4*)(&Xs[k * 64 + tx * 4]);
    *(float4*)wv = *(const float4*)(&Ws[k * 64 + ty * 4]);
#pragma unroll
    for (int i = 0; i < 4; ++i)
#pragma unroll
      for (int j = 0; j < 4; ++j)
        acc[i][j] = fmaf(wv[i], xv[j], acc[i][j]);
  }

#pragma unroll
  for (int i = 0; i < 4; ++i) {
    const int e = e0 + ty * 4 + i;
    const float bp = b_proj[e];
    float vv[4];
#pragma unroll
    for (int j = 0; j < 4; ++j) vv[j] = acc[i][j] + bp;
    *(float4*)(outp + ((size_t)b * CH + e) * NSP + n0 + tx * 4) = *(float4*)vv;
  }
}

// ---------------- launch ----------------

extern "C" void kernel_launch(void* const* d_in, const int* in_sizes, int n_in,
                              void* d_out, int out_size, void* d_ws, size_t ws_size,
                              hipStream_t stream) {
  const float* x      = (const float*)d_in[0];
  const float* w_qkv  = (const float*)d_in[1];
  const float* w_gate = (const float*)d_in[2];
  const float* b_gate = (const float*)d_in[3];
  const float* w_proj = (const float*)d_in[4];
  const float* b_proj = (const float*)d_in[5];
  float* outp = (float*)d_out;

  const size_t SZ = (size_t)BATCH * CH * NSP;
  float* Q = (float*)d_ws;   // also receives corr(attn,V) in-place
  float* K = Q + SZ;
  float* V = K + SZ;
  float* T = V + SZ;

  dim3 g1(NSP / 64, 8, BATCH);
  gemm_qkvg<<<g1, 256, 0, stream>>>(x, w_qkv, w_gate, b_gate, Q, K, V, T);

  fft_attn_fused<<<NIMG, NT, 0, stream>>>(Q, K, V, Q);

  dim3 g2(NSP / 64, 2, BATCH);
  gemm_proj<<<g2, 256, 0, stream>>>(Q, T, w_proj, b_proj, outp);
}

// Round 4
// 457.789 us; speedup vs baseline: 1.9494x; 1.3253x over previous
//
#include <hip/hip_runtime.h>
#include <math.h>

// CirculantAttention on MI355X.
//   attn = softmax_n( N^{-3/2} * circ_corr(Xq, Xk) )   per (b,c) image
//   out  = (1/N)    *  circ_corr(attn, Xv)
// GEMMs in spatial domain via bf16x3-split MFMA (hi/lo decomposition, 3 MFMA
// products ~ fp32 accuracy). FFT: 8x16 two-phase in-register engine.

constexpr int CH    = 128;
constexpr int NSP   = 128 * 128;   // 16384
constexpr int BATCH = 8;
constexpr int NIMG  = BATCH * CH;  // 1024
constexpr int RS    = 130;         // fft complex row stride
constexpr int NT    = 1024;        // fft threads (16 waves)
constexpr int NW    = NT / 64;

// ======================= MFMA GEMM machinery =======================

typedef short short8 __attribute__((ext_vector_type(8)));
typedef float f32x4  __attribute__((ext_vector_type(4)));
union U8 { unsigned u[4]; short8 s; };

__device__ __forceinline__ unsigned bf16r(float x) {   // RNE -> low 16 bits
  unsigned u = __float_as_uint(x);
  return (u + 0x7FFFu + ((u >> 16) & 1u)) >> 16;
}

// Split a float pair (e0=k even, e1=k+1) into hi-word / lo-word (bf16x2 each)
__device__ __forceinline__ void split_pair(float e0, float e1,
                                           unsigned& hi, unsigned& lo) {
  const unsigned u0 = __float_as_uint(e0), u1 = __float_as_uint(e1);
  hi = (u0 >> 16) | (u1 & 0xFFFF0000u);
  const float r0 = e0 - __uint_as_float(u0 & 0xFFFF0000u);
  const float r1 = e1 - __uint_as_float(u1 & 0xFFFF0000u);
  lo = bf16r(r0) | (bf16r(r1) << 16);
}

// Build A fragment (hi+lo) for this lane from a global fp32 row (k-contiguous)
__device__ __forceinline__ void load_a_frag(const float* wr, short8& ah, short8& al) {
  const float4 wa = *(const float4*)wr;
  const float4 wb = *(const float4*)(wr + 4);
  U8 hi, lo;
  split_pair(wa.x, wa.y, hi.u[0], lo.u[0]);
  split_pair(wa.z, wa.w, hi.u[1], lo.u[1]);
  split_pair(wb.x, wb.y, hi.u[2], lo.u[2]);
  split_pair(wb.z, wb.w, hi.u[3], lo.u[3]);
  ah = hi.s; al = lo.s;
}

// Shared GEMM core. xs: unsigned[16896] LDS (bf16 hi plane [0,8192), lo plane
// [8192,16384); reused afterwards as fp32 bounce 128x132).
// Computes D[128 rows x 128 cols] = W(128x128,k-contig rows) @ Xtile, where the
// X tile must already be staged in xs planes ([n][k] bf16, XOR-swizzled words).
__device__ __forceinline__ void mfma_core(unsigned* xs, const float* wbase,
                                          f32x4 acc[4][4], int tid) {
  const int lane = tid & 63, wid = tid >> 6;
  const int mb = (wid >> 1) * 64;
  const int nb = (wid & 1) * 64;
  const int lm = lane & 15, quad = lane >> 4;
#pragma unroll
  for (int kg = 0; kg < 4; ++kg) {
    short8 ah[4], al[4], bh[4], bl[4];
#pragma unroll
    for (int mf = 0; mf < 4; ++mf) {
      const float* wr = wbase + (size_t)(mb + mf * 16 + lm) * CH + kg * 32 + quad * 8;
      load_a_frag(wr, ah[mf], al[mf]);
    }
    const int kwb = (kg * 16 + quad * 4) ^ (lm << 2);
#pragma unroll
    for (int nf = 0; nf < 4; ++nf) {
      const unsigned* p = xs + (nb + nf * 16 + lm) * 64 + kwb;
      bh[nf] = *(const short8*)p;
      bl[nf] = *(const short8*)(p + 8192);
    }
    // term-major order: same-acc MFMAs spaced 16 apart (no dep stalls)
#pragma unroll
    for (int mf = 0; mf < 4; ++mf)
#pragma unroll
      for (int nf = 0; nf < 4; ++nf)
        acc[mf][nf] = __builtin_amdgcn_mfma_f32_16x16x32_bf16(al[mf], bh[nf], acc[mf][nf], 0, 0, 0);
#pragma unroll
    for (int mf = 0; mf < 4; ++mf)
#pragma unroll
      for (int nf = 0; nf < 4; ++nf)
        acc[mf][nf] = __builtin_amdgcn_mfma_f32_16x16x32_bf16(ah[mf], bl[nf], acc[mf][nf], 0, 0, 0);
#pragma unroll
    for (int mf = 0; mf < 4; ++mf)
#pragma unroll
      for (int nf = 0; nf < 4; ++nf)
        acc[mf][nf] = __builtin_amdgcn_mfma_f32_16x16x32_bf16(ah[mf], bh[nf], acc[mf][nf], 0, 0, 0);
  }
}

// Scatter accumulators into the fp32 bounce buffer (row stride 132)
__device__ __forceinline__ void acc_to_bounce(float* bounce, f32x4 acc[4][4], int tid) {
  const int lane = tid & 63, wid = tid >> 6;
  const int mb = (wid >> 1) * 64;
  const int nb = (wid & 1) * 64;
  const int lm = lane & 15, quad = lane >> 4;
#pragma unroll
  for (int mf = 0; mf < 4; ++mf)
#pragma unroll
    for (int nf = 0; nf < 4; ++nf) {
      const int col = nb + nf * 16 + lm;
      const int r0 = mb + mf * 16 + quad * 4;
#pragma unroll
      for (int i = 0; i < 4; ++i)
        bounce[(r0 + i) * 132 + col] = acc[mf][nf][i];
    }
}

// ---------------- GEMM 1: per batch, 4 output tensors ----------------
// grid (128 n-tiles, 4 dsel, 8 batch); dsel 0..2 -> Q/K/V, 3 -> silu gate

__global__ __launch_bounds__(256, 2)
void gemm_qkvg(const float* __restrict__ x, const float* __restrict__ w_qkv,
               const float* __restrict__ w_gate, const float* __restrict__ b_gate,
               float* __restrict__ Q, float* __restrict__ K,
               float* __restrict__ V, float* __restrict__ T) {
  __shared__ __align__(16) unsigned xs[16896];   // 67,584 B
  const int tid = threadIdx.x;
  const int n0 = blockIdx.x * 128;
  const int dsel = blockIdx.y;
  const int b = blockIdx.z;
  const float* xb = x + (size_t)b * CH * NSP;

  // stage X[k][n0..n0+127] -> [n][k] bf16 hi/lo planes (k-pair b32, XOR swizzle)
  {
    const int tn = tid >> 3;          // n-quad 0..31
    const int tk = tid & 7;
#pragma unroll
    for (int i = 0; i < 8; ++i) {
      const int k = 2 * tk + 16 * i;
      const float* p0 = xb + (size_t)k * NSP + n0 + 4 * tn;
      const float4 a = *(const float4*)p0;
      const float4 c = *(const float4*)(p0 + NSP);
      const float a4[4] = {a.x, a.y, a.z, a.w};
      const float c4[4] = {c.x, c.y, c.z, c.w};
      const int kw = tk + 8 * i;
#pragma unroll
      for (int j = 0; j < 4; ++j) {
        const int nn = 4 * tn + j;
        unsigned hi, lo;
        split_pair(a4[j], c4[j], hi, lo);
        const int kws = kw ^ ((nn & 15) << 2);
        xs[nn * 64 + kws] = hi;
        xs[8192 + nn * 64 + kws] = lo;
      }
    }
  }
  __syncthreads();

  const float* wbase = (dsel == 3) ? w_gate : (w_qkv + (size_t)dsel * CH * CH);
  f32x4 acc[4][4];
#pragma unroll
  for (int mf = 0; mf < 4; ++mf)
#pragma unroll
    for (int nf = 0; nf < 4; ++nf) acc[mf][nf] = (f32x4){0.f, 0.f, 0.f, 0.f};

  mfma_core(xs, wbase, acc, tid);

  __syncthreads();                       // xs planes dead; reuse as bounce
  float* bounce = (float*)xs;
  acc_to_bounce(bounce, acc, tid);
  __syncthreads();

  float* targ = (dsel == 0) ? Q : (dsel == 1) ? K : (dsel == 2) ? V : T;
  const int rr = tid >> 5;               // 0..7
  const int c4i = (tid & 31) * 4;
#pragma unroll
  for (int i = 0; i < 16; ++i) {
    const int row = rr + 8 * i;
    float4 v = *(const float4*)(bounce + row * 132 + c4i);
    if (dsel == 3) {
      const float bg = b_gate[row];
      float e[4] = {v.x, v.y, v.z, v.w};
#pragma unroll
      for (int j = 0; j < 4; ++j) {
        const float g = e[j] + bg;
        e[j] = g / (1.0f + __expf(-g));
      }
      v = make_float4(e[0], e[1], e[2], e[3]);
    }
    *(float4*)(targ + ((size_t)b * CH + row) * NSP + n0 + c4i) = v;
  }
}

// ---------------- GEMM 2: w_proj @ (oc .* t) + b_proj ----------------
// grid (128 n-tiles, 8 batch)

__global__ __launch_bounds__(256, 2)
void gemm_proj(const float* __restrict__ OC, const float* __restrict__ Tn,
               const float* __restrict__ w_proj, const float* __restrict__ b_proj,
               float* __restrict__ outp) {
  __shared__ __align__(16) unsigned xs[16896];
  const int tid = threadIdx.x;
  const int n0 = blockIdx.x * 128;
  const int b = blockIdx.y;
  const float* ob = OC + (size_t)b * CH * NSP;
  const float* tb = Tn + (size_t)b * CH * NSP;

  {
    const int tn = tid >> 3;
    const int tk = tid & 7;
#pragma unroll
    for (int i = 0; i < 8; ++i) {
      const int k = 2 * tk + 16 * i;
      const float* po = ob + (size_t)k * NSP + n0 + 4 * tn;
      const float* pt = tb + (size_t)k * NSP + n0 + 4 * tn;
      const float4 o0 = *(const float4*)po;
      const float4 o1 = *(const float4*)(po + NSP);
      const float4 t0 = *(const float4*)pt;
      const float4 t1 = *(const float4*)(pt + NSP);
      const float z0[4] = {o0.x * t0.x, o0.y * t0.y, o0.z * t0.z, o0.w * t0.w};
      const float z1[4] = {o1.x * t1.x, o1.y * t1.y, o1.z * t1.z, o1.w * t1.w};
      const int kw = tk + 8 * i;
#pragma unroll
      for (int j = 0; j < 4; ++j) {
        const int nn = 4 * tn + j;
        unsigned hi, lo;
        split_pair(z0[j], z1[j], hi, lo);
        const int kws = kw ^ ((nn & 15) << 2);
        xs[nn * 64 + kws] = hi;
        xs[8192 + nn * 64 + kws] = lo;
      }
    }
  }
  __syncthreads();

  f32x4 acc[4][4];
#pragma unroll
  for (int mf = 0; mf < 4; ++mf)
#pragma unroll
    for (int nf = 0; nf < 4; ++nf) acc[mf][nf] = (f32x4){0.f, 0.f, 0.f, 0.f};

  mfma_core(xs, w_proj, acc, tid);

  __syncthreads();
  float* bounce = (float*)xs;
  acc_to_bounce(bounce, acc, tid);
  __syncthreads();

  const int rr = tid >> 5;
  const int c4i = (tid & 31) * 4;
#pragma unroll
  for (int i = 0; i < 16; ++i) {
    const int row = rr + 8 * i;
    const float bp = b_proj[row];
    float4 v = *(const float4*)(bounce + row * 132 + c4i);
    v.x += bp; v.y += bp; v.z += bp; v.w += bp;
    *(float4*)(outp + ((size_t)b * CH + row) * NSP + n0 + c4i) = v;
  }
}

// ======================= FFT attention (unchanged engine) =======================

__device__ __forceinline__ float2 cmul(float2 a, float2 b) {
  return make_float2(fmaf(a.x, b.x, -(a.y * b.y)), fmaf(a.x, b.y, a.y * b.x));
}
#define CADD(a,b) make_float2((a).x+(b).x,(a).y+(b).y)
#define CSUB(a,b) make_float2((a).x-(b).x,(a).y-(b).y)
#define MULNI(t)  make_float2((t).y, -(t).x)
constexpr float C45 = 0.7071067811865476f;

__device__ __forceinline__ void fft8(float2* x) {
  float2 t;
  t = CSUB(x[0],x[4]); x[0]=CADD(x[0],x[4]); x[4]=t;
  t = CSUB(x[1],x[5]); x[1]=CADD(x[1],x[5]); x[5]=make_float2(C45*(t.x+t.y), C45*(t.y-t.x));
  t = CSUB(x[2],x[6]); x[2]=CADD(x[2],x[6]); x[6]=MULNI(t);
  t = CSUB(x[3],x[7]); x[3]=CADD(x[3],x[7]); x[7]=make_float2(C45*(t.y-t.x), -C45*(t.x+t.y));
  t = CSUB(x[0],x[2]); x[0]=CADD(x[0],x[2]); x[2]=t;
  t = CSUB(x[1],x[3]); x[1]=CADD(x[1],x[3]); x[3]=MULNI(t);
  t = CSUB(x[4],x[6]); x[4]=CADD(x[4],x[6]); x[6]=t;
  t = CSUB(x[5],x[7]); x[5]=CADD(x[5],x[7]); x[7]=MULNI(t);
  t = CSUB(x[0],x[1]); x[0]=CADD(x[0],x[1]); x[1]=t;
  t = CSUB(x[2],x[3]); x[2]=CADD(x[2],x[3]); x[3]=t;
  t = CSUB(x[4],x[5]); x[4]=CADD(x[4],x[5]); x[5]=t;
  t = CSUB(x[6],x[7]); x[6]=CADD(x[6],x[7]); x[7]=t;
}

__device__ __forceinline__ void fft16(float2* z) {
  float2 t;
  t=CSUB(z[0],z[8]);   z[0]=CADD(z[0],z[8]);   z[8]=t;
  t=CSUB(z[1],z[9]);   z[1]=CADD(z[1],z[9]);   z[9]=cmul(t,  make_float2( 0.9238795325f,-0.3826834324f));
  t=CSUB(z[2],z[10]);  z[2]=CADD(z[2],z[10]);  z[10]=make_float2(C45*(t.x+t.y), C45*(t.y-t.x));
  t=CSUB(z[3],z[11]);  z[3]=CADD(z[3],z[11]);  z[11]=cmul(t, make_float2( 0.3826834324f,-0.9238795325f));
  t=CSUB(z[4],z[12]);  z[4]=CADD(z[4],z[12]);  z[12]=MULNI(t);
  t=CSUB(z[5],z[13]);  z[5]=CADD(z[5],z[13]);  z[13]=cmul(t, make_float2(-0.3826834324f,-0.9238795325f));
  t=CSUB(z[6],z[14]);  z[6]=CADD(z[6],z[14]);  z[14]=make_float2(C45*(t.y-t.x), -C45*(t.x+t.y));
  t=CSUB(z[7],z[15]);  z[7]=CADD(z[7],z[15]);  z[15]=cmul(t, make_float2(-0.9238795325f,-0.3826834324f));
  t=CSUB(z[0],z[4]);   z[0]=CADD(z[0],z[4]);   z[4]=t;
  t=CSUB(z[1],z[5]);   z[1]=CADD(z[1],z[5]);   z[5]=make_float2(C45*(t.x+t.y), C45*(t.y-t.x));
  t=CSUB(z[2],z[6]);   z[2]=CADD(z[2],z[6]);   z[6]=MULNI(t);
  t=CSUB(z[3],z[7]);   z[3]=CADD(z[3],z[7]);   z[7]=make_float2(C45*(t.y-t.x), -C45*(t.x+t.y));
  t=CSUB(z[8],z[12]);  z[8]=CADD(z[8],z[12]);  z[12]=t;
  t=CSUB(z[9],z[13]);  z[9]=CADD(z[9],z[13]);  z[13]=make_float2(C45*(t.x+t.y), C45*(t.y-t.x));
  t=CSUB(z[10],z[14]); z[10]=CADD(z[10],z[14]); z[14]=MULNI(t);
  t=CSUB(z[11],z[15]); z[11]=CADD(z[11],z[15]); z[15]=make_float2(C45*(t.y-t.x), -C45*(t.x+t.y));
  t=CSUB(z[0],z[2]);   z[0]=CADD(z[0],z[2]);   z[2]=t;
  t=CSUB(z[1],z[3]);   z[1]=CADD(z[1],z[3]);   z[3]=MULNI(t);
  t=CSUB(z[4],z[6]);   z[4]=CADD(z[4],z[6]);   z[6]=t;
  t=CSUB(z[5],z[7]);   z[5]=CADD(z[5],z[7]);   z[7]=MULNI(t);
  t=CSUB(z[8],z[10]);  z[8]=CADD(z[8],z[10]);  z[10]=t;
  t=CSUB(z[9],z[11]);  z[9]=CADD(z[9],z[11]);  z[11]=MULNI(t);
  t=CSUB(z[12],z[14]); z[12]=CADD(z[12],z[14]); z[14]=t;
  t=CSUB(z[13],z[15]); z[13]=CADD(z[13],z[15]); z[15]=MULNI(t);
  t=CSUB(z[0],z[1]);   z[0]=CADD(z[0],z[1]);   z[1]=t;
  t=CSUB(z[2],z[3]);   z[2]=CADD(z[2],z[3]);   z[3]=t;
  t=CSUB(z[4],z[5]);   z[4]=CADD(z[4],z[5]);   z[5]=t;
  t=CSUB(z[6],z[7]);   z[6]=CADD(z[6],z[7]);   z[7]=t;
  t=CSUB(z[8],z[9]);   z[8]=CADD(z[8],z[9]);   z[9]=t;
  t=CSUB(z[10],z[11]); z[10]=CADD(z[10],z[11]); z[11]=t;
  t=CSUB(z[12],z[13]); z[12]=CADD(z[12],z[13]); z[13]=t;
  t=CSUB(z[14],z[15]); z[14]=CADD(z[14],z[15]); z[15]=t;
}

template<int SPT, int SLN>
__device__ __forceinline__ void fft_pass(float2* img, const float2* tw,
                                         int lane, int wid) {
  const int n2 = lane & 15, rr = lane >> 4;
  constexpr int br3[8] = {0,4,2,6,1,5,3,7};
#pragma unroll
  for (int u = 0; u < 2; ++u) {
    const int lb = SLN * (wid * 8 + u * 4 + rr);
    float2 x[8];
#pragma unroll
    for (int n1 = 0; n1 < 8; ++n1) x[n1] = img[lb + SPT * (16 * n1 + n2)];
    fft8(x);
#pragma unroll
    for (int m = 0; m < 8; ++m) {
      const int k1 = br3[m];
      const float2 y = (k1 == 0) ? x[m] : cmul(x[m], tw[k1 - 1]);
      img[lb + SPT * (16 * k1 + (n2 ^ k1))] = y;
    }
  }
  const int k1 = lane & 7;
  const int lb = SLN * (wid * 8 + (lane >> 3));
  const int kb = 16 * k1;
  float2 z[16];
#pragma unroll
  for (int j = 0; j < 16; ++j) z[j] = img[lb + SPT * (kb + (j ^ k1))];
  fft16(z);
  constexpr int br4[16] = {0,8,4,12,2,10,6,14,1,9,5,13,3,11,7,15};
#pragma unroll
  for (int m = 0; m < 16; ++m) img[lb + SPT * (k1 + 8 * br4[m])] = z[m];
}

__device__ __forceinline__ void fft2d(float2* img, const float2* tw,
                                      int lane, int wid) {
  fft_pass<1, RS>(img, tw, lane, wid);
  __syncthreads();
  fft_pass<RS, 1>(img, tw, lane, wid);
  __syncthreads();
}

__device__ __forceinline__ void cross_spectrum(float2* img, int tid) {
  for (int idx = tid; idx < NSP; idx += NT) {
    const int fr = idx >> 7, fc = idx & 127;
    const int gr = (128 - fr) & 127, gc = (128 - fc) & 127;
    const int gidx = (gr << 7) | gc;
    if (idx > gidx) continue;
    const int f = fr * RS + fc;
    const float2 zf = img[f];
    if (idx == gidx) {
      img[f] = make_float2(zf.x * zf.y, 0.0f);
    } else {
      const int g = gr * RS + gc;
      const float2 zg = img[g];
      const float qr = 0.5f * (zf.x + zg.x), qi = 0.5f * (zf.y - zg.y);
      const float kr = 0.5f * (zf.y + zg.y), ki = 0.5f * (zg.x - zf.x);
      const float yr = qr * kr + qi * ki;
      const float yi = qr * ki - qi * kr;
      img[f] = make_float2(yr, -yi);
      img[g] = make_float2(yr, yi);
    }
  }
}

__global__ __launch_bounds__(NT)
void fft_attn_fused(const float* __restrict__ Qin, const float* __restrict__ Kin,
                    const float* __restrict__ Vin, float* __restrict__ Out) {
  __shared__ float2 img[128 * RS];
  __shared__ float red[2 * NW];
  const int tid = threadIdx.x, lane = tid & 63, wid = tid >> 6;
  const size_t off = (size_t)blockIdx.x * NSP;

  float2 tw[7];
  {
    const int n2 = lane & 15;
#pragma unroll
    for (int k = 1; k < 8; ++k) {
      float s, c;
      sincosf(6.283185307179586f * (float)(n2 * k) * (1.0f / 128.0f), &s, &c);
      tw[k - 1] = make_float2(c, -s);
    }
  }

#pragma unroll
  for (int i = 0; i < 4; ++i) {
    const int e = (tid + i * NT) * 4;
    const float4 q4 = *(const float4*)(Qin + off + e);
    const float4 k4 = *(const float4*)(Kin + off + e);
    float2* p = img + (e >> 7) * RS + (e & 127);
    p[0] = make_float2(q4.x, k4.x); p[1] = make_float2(q4.y, k4.y);
    p[2] = make_float2(q4.z, k4.z); p[3] = make_float2(q4.w, k4.w);
  }
  __syncthreads();

  fft2d(img, tw, lane, wid);
  cross_spectrum(img, tid);
  __syncthreads();
  fft2d(img, tw, lane, wid);

  const float scale = 1.0f / 2097152.0f;
  float m = -3.0e38f;
#pragma unroll
  for (int i = 0; i < 16; ++i) {
    const int e = tid + i * NT;
    m = fmaxf(m, img[(e >> 7) * RS + (e & 127)].x);
  }
#pragma unroll
  for (int s = 32; s >= 1; s >>= 1) m = fmaxf(m, __shfl_xor(m, s, 64));
  if (lane == 0) red[wid] = m;
  __syncthreads();
  m = red[0];
#pragma unroll
  for (int w = 1; w < NW; ++w) m = fmaxf(m, red[w]);
  float sum = 0.0f;
#pragma unroll
  for (int i = 0; i < 16; ++i) {
    const int e = tid + i * NT;
    float2* p = img + (e >> 7) * RS + (e & 127);
    const float ex = __expf((p->x - m) * scale);
    p->x = ex;
    sum += ex;
  }
#pragma unroll
  for (int s = 32; s >= 1; s >>= 1) sum += __shfl_xor(sum, s, 64);
  if (lane == 0) red[NW + wid] = sum;
  __syncthreads();
  float tot = 0.0f;
#pragma unroll
  for (int w = 0; w < NW; ++w) tot += red[NW + w];
  const float inv = 1.0f / tot;

#pragma unroll
  for (int i = 0; i < 4; ++i) {
    const int e = (tid + i * NT) * 4;
    const float4 v4 = *(const float4*)(Vin + off + e);
    float2* p = img + (e >> 7) * RS + (e & 127);
    p[0] = make_float2(p[0].x * inv, v4.x);
    p[1] = make_float2(p[1].x * inv, v4.y);
    p[2] = make_float2(p[2].x * inv, v4.z);
    p[3] = make_float2(p[3].x * inv, v4.w);
  }
  __syncthreads();

  fft2d(img, tw, lane, wid);
  cross_spectrum(img, tid);
  __syncthreads();
  fft2d(img, tw, lane, wid);

  const float os = 1.0f / 16384.0f;
#pragma unroll
  for (int i = 0; i < 4; ++i) {
    const int e = (tid + i * NT) * 4;
    float2* p = img + (e >> 7) * RS + (e & 127);
    float4 o;
    o.x = p[0].x * os; o.y = p[1].x * os; o.z = p[2].x * os; o.w = p[3].x * os;
    *(float4*)(Out + off + e) = o;
  }
}

// ---------------- launch ----------------

extern "C" void kernel_launch(void* const* d_in, const int* in_sizes, int n_in,
                              void* d_out, int out_size, void* d_ws, size_t ws_size,
                              hipStream_t stream) {
  const float* x      = (const float*)d_in[0];
  const float* w_qkv  = (const float*)d_in[1];
  const float* w_gate = (const float*)d_in[2];
  const float* b_gate = (const float*)d_in[3];
  const float* w_proj = (const float*)d_in[4];
  const float* b_proj = (const float*)d_in[5];
  float* outp = (float*)d_out;

  const size_t SZ = (size_t)BATCH * CH * NSP;
  float* Q = (float*)d_ws;   // also receives corr(attn,V) in-place
  float* K = Q + SZ;
  float* V = K + SZ;
  float* T = V + SZ;

  dim3 g1(128, 4, BATCH);
  gemm_qkvg<<<g1, 256, 0, stream>>>(x, w_qkv, w_gate, b_gate, Q, K, V, T);

  fft_attn_fused<<<NIMG, NT, 0, stream>>>(Q, K, V, Q);

  dim3 g2(128, BATCH);
  gemm_proj<<<g2, 256, 0, stream>>>(Q, T, w_proj, b_proj, outp);
}

// Round 5
// 453.903 us; speedup vs baseline: 1.9661x; 1.0086x over previous
//
#include <hip/hip_runtime.h>
#include <math.h>

// CirculantAttention on MI355X.
//   attn = softmax_n( N^{-3/2} * circ_corr(Xq, Xk) )   per (b,c) image
//   out  = (1/N)    *  circ_corr(attn, Xv)
// GEMMs in spatial domain via bf16x3-split MFMA. FFT: 8x16 two-phase
// in-register engine; exp fused into the inverse col pass; softmax
// normalization folded into the final output scale (linearity).

constexpr int CH    = 128;
constexpr int NSP   = 128 * 128;   // 16384
constexpr int BATCH = 8;
constexpr int NIMG  = BATCH * CH;  // 1024
constexpr int RS    = 130;         // fft complex row stride
constexpr int NT    = 1024;        // fft threads (16 waves)
constexpr int NW    = NT / 64;

// ======================= MFMA GEMM machinery =======================

typedef short short8 __attribute__((ext_vector_type(8)));
typedef float f32x4  __attribute__((ext_vector_type(4)));
union U8 { unsigned u[4]; short8 s; };

__device__ __forceinline__ unsigned bf16r(float x) {   // RNE -> low 16 bits
  unsigned u = __float_as_uint(x);
  return (u + 0x7FFFu + ((u >> 16) & 1u)) >> 16;
}

__device__ __forceinline__ void split_pair(float e0, float e1,
                                           unsigned& hi, unsigned& lo) {
  const unsigned u0 = __float_as_uint(e0), u1 = __float_as_uint(e1);
  hi = (u0 >> 16) | (u1 & 0xFFFF0000u);
  const float r0 = e0 - __uint_as_float(u0 & 0xFFFF0000u);
  const float r1 = e1 - __uint_as_float(u1 & 0xFFFF0000u);
  lo = bf16r(r0) | (bf16r(r1) << 16);
}

__device__ __forceinline__ void load_a_frag(const float* wr, short8& ah, short8& al) {
  const float4 wa = *(const float4*)wr;
  const float4 wb = *(const float4*)(wr + 4);
  U8 hi, lo;
  split_pair(wa.x, wa.y, hi.u[0], lo.u[0]);
  split_pair(wa.z, wa.w, hi.u[1], lo.u[1]);
  split_pair(wb.x, wb.y, hi.u[2], lo.u[2]);
  split_pair(wb.z, wb.w, hi.u[3], lo.u[3]);
  ah = hi.s; al = lo.s;
}

// xs: bf16 hi plane [0,8192), lo plane [8192,16384), XOR-swizzled words.
__device__ __forceinline__ void mfma_core(const unsigned* xs, const float* wbase,
                                          f32x4 acc[4][4], int tid) {
  const int lane = tid & 63, wid = tid >> 6;
  const int mb = (wid >> 1) * 64;
  const int nb = (wid & 1) * 64;
  const int lm = lane & 15, quad = lane >> 4;
#pragma unroll
  for (int kg = 0; kg < 4; ++kg) {
    short8 ah[4], al[4], bh[4], bl[4];
#pragma unroll
    for (int mf = 0; mf < 4; ++mf) {
      const float* wr = wbase + (size_t)(mb + mf * 16 + lm) * CH + kg * 32 + quad * 8;
      load_a_frag(wr, ah[mf], al[mf]);
    }
    const int kwb = (kg * 16 + quad * 4) ^ (lm << 2);
#pragma unroll
    for (int nf = 0; nf < 4; ++nf) {
      const unsigned* p = xs + (nb + nf * 16 + lm) * 64 + kwb;
      bh[nf] = *(const short8*)p;
      bl[nf] = *(const short8*)(p + 8192);
    }
#pragma unroll
    for (int mf = 0; mf < 4; ++mf)
#pragma unroll
      for (int nf = 0; nf < 4; ++nf)
        acc[mf][nf] = __builtin_amdgcn_mfma_f32_16x16x32_bf16(al[mf], bh[nf], acc[mf][nf], 0, 0, 0);
#pragma unroll
    for (int mf = 0; mf < 4; ++mf)
#pragma unroll
      for (int nf = 0; nf < 4; ++nf)
        acc[mf][nf] = __builtin_amdgcn_mfma_f32_16x16x32_bf16(ah[mf], bl[nf], acc[mf][nf], 0, 0, 0);
#pragma unroll
    for (int mf = 0; mf < 4; ++mf)
#pragma unroll
      for (int nf = 0; nf < 4; ++nf)
        acc[mf][nf] = __builtin_amdgcn_mfma_f32_16x16x32_bf16(ah[mf], bh[nf], acc[mf][nf], 0, 0, 0);
  }
}

__device__ __forceinline__ void acc_to_bounce(float* bounce, f32x4 acc[4][4], int tid) {
  const int lane = tid & 63, wid = tid >> 6;
  const int mb = (wid >> 1) * 64;
  const int nb = (wid & 1) * 64;
  const int lm = lane & 15, quad = lane >> 4;
#pragma unroll
  for (int mf = 0; mf < 4; ++mf)
#pragma unroll
    for (int nf = 0; nf < 4; ++nf) {
      const int col = nb + nf * 16 + lm;
      const int r0 = mb + mf * 16 + quad * 4;
#pragma unroll
      for (int i = 0; i < 4; ++i)
        bounce[(r0 + i) * 132 + col] = acc[mf][nf][i];
    }
}

// ---------------- GEMM 1: one block -> Q,K,V,T for one (b, n-tile) ----------------
// X staged once; 4 sequential MFMA cores against the resident planes.

__global__ __launch_bounds__(256, 2)
void gemm_qkvg(const float* __restrict__ x, const float* __restrict__ w_qkv,
               const float* __restrict__ w_gate, const float* __restrict__ b_gate,
               float* __restrict__ Q, float* __restrict__ K,
               float* __restrict__ V, float* __restrict__ T) {
  __shared__ __align__(16) unsigned xs[16896];   // 67,584 B -> 2 blocks/CU
  const int tid = threadIdx.x;
  const int n0 = blockIdx.x * 128;
  const int b  = blockIdx.y;
  const float* xb = x + (size_t)b * CH * NSP;

  {
    const int tn = tid >> 3;
    const int tk = tid & 7;
#pragma unroll
    for (int i = 0; i < 8; ++i) {
      const int k = 2 * tk + 16 * i;
      const float* p0 = xb + (size_t)k * NSP + n0 + 4 * tn;
      const float4 a = *(const float4*)p0;
      const float4 c = *(const float4*)(p0 + NSP);
      const float a4[4] = {a.x, a.y, a.z, a.w};
      const float c4[4] = {c.x, c.y, c.z, c.w};
      const int kw = tk + 8 * i;
#pragma unroll
      for (int j = 0; j < 4; ++j) {
        const int nn = 4 * tn + j;
        unsigned hi, lo;
        split_pair(a4[j], c4[j], hi, lo);
        const int kws = kw ^ ((nn & 15) << 2);
        xs[nn * 64 + kws] = hi;
        xs[8192 + nn * 64 + kws] = lo;
      }
    }
  }
  __syncthreads();

  const int lane = tid & 63, wid = tid >> 6;
  const int mb = (wid >> 1) * 64, nb = (wid & 1) * 64;
  const int lm = lane & 15, quad = lane >> 4;
  float* const targs[4] = {Q, K, V, T};

#pragma unroll 1
  for (int dsel = 0; dsel < 4; ++dsel) {
    const float* wbase = (dsel == 3) ? w_gate : (w_qkv + (size_t)dsel * CH * CH);
    f32x4 acc[4][4];
#pragma unroll
    for (int mf = 0; mf < 4; ++mf)
#pragma unroll
      for (int nf = 0; nf < 4; ++nf) acc[mf][nf] = (f32x4){0.f, 0.f, 0.f, 0.f};

    mfma_core(xs, wbase, acc, tid);

    // direct store: 16 consecutive cols per lane-group; L2 merges rows
    float* targ = targs[dsel];
#pragma unroll
    for (int mf = 0; mf < 4; ++mf) {
#pragma unroll
      for (int i = 0; i < 4; ++i) {
        const int row = mb + mf * 16 + quad * 4 + i;
        float* orow = targ + ((size_t)b * CH + row) * NSP + n0 + nb + lm;
        if (dsel == 3) {
          const float bg = b_gate[row];
#pragma unroll
          for (int nf = 0; nf < 4; ++nf) {
            const float g = acc[mf][nf][i] + bg;
            orow[nf * 16] = g / (1.0f + __expf(-g));
          }
        } else {
#pragma unroll
          for (int nf = 0; nf < 4; ++nf) orow[nf * 16] = acc[mf][nf][i];
        }
      }
    }
  }
}

// ---------------- GEMM 2: w_proj @ (oc .* t) + b_proj ----------------

__global__ __launch_bounds__(256, 2)
void gemm_proj(const float* __restrict__ OC, const float* __restrict__ Tn,
               const float* __restrict__ w_proj, const float* __restrict__ b_proj,
               float* __restrict__ outp) {
  __shared__ __align__(16) unsigned xs[16896];
  const int tid = threadIdx.x;
  const int n0 = blockIdx.x * 128;
  const int b = blockIdx.y;
  const float* ob = OC + (size_t)b * CH * NSP;
  const float* tb = Tn + (size_t)b * CH * NSP;

  {
    const int tn = tid >> 3;
    const int tk = tid & 7;
#pragma unroll
    for (int i = 0; i < 8; ++i) {
      const int k = 2 * tk + 16 * i;
      const float* po = ob + (size_t)k * NSP + n0 + 4 * tn;
      const float* pt = tb + (size_t)k * NSP + n0 + 4 * tn;
      const float4 o0 = *(const float4*)po;
      const float4 o1 = *(const float4*)(po + NSP);
      const float4 t0 = *(const float4*)pt;
      const float4 t1 = *(const float4*)(pt + NSP);
      const float z0[4] = {o0.x * t0.x, o0.y * t0.y, o0.z * t0.z, o0.w * t0.w};
      const float z1[4] = {o1.x * t1.x, o1.y * t1.y, o1.z * t1.z, o1.w * t1.w};
      const int kw = tk + 8 * i;
#pragma unroll
      for (int j = 0; j < 4; ++j) {
        const int nn = 4 * tn + j;
        unsigned hi, lo;
        split_pair(z0[j], z1[j], hi, lo);
        const int kws = kw ^ ((nn & 15) << 2);
        xs[nn * 64 + kws] = hi;
        xs[8192 + nn * 64 + kws] = lo;
      }
    }
  }
  __syncthreads();

  f32x4 acc[4][4];
#pragma unroll
  for (int mf = 0; mf < 4; ++mf)
#pragma unroll
    for (int nf = 0; nf < 4; ++nf) acc[mf][nf] = (f32x4){0.f, 0.f, 0.f, 0.f};

  mfma_core(xs, w_proj, acc, tid);

  __syncthreads();
  float* bounce = (float*)xs;
  acc_to_bounce(bounce, acc, tid);
  __syncthreads();

  const int rr = tid >> 5;
  const int c4i = (tid & 31) * 4;
#pragma unroll
  for (int i = 0; i < 16; ++i) {
    const int row = rr + 8 * i;
    const float bp = b_proj[row];
    float4 v = *(const float4*)(bounce + row * 132 + c4i);
    v.x += bp; v.y += bp; v.z += bp; v.w += bp;
    *(float4*)(outp + ((size_t)b * CH + row) * NSP + n0 + c4i) = v;
  }
}

// ======================= FFT attention =======================

__device__ __forceinline__ float2 cmul(float2 a, float2 b) {
  return make_float2(fmaf(a.x, b.x, -(a.y * b.y)), fmaf(a.x, b.y, a.y * b.x));
}
#define CADD(a,b) make_float2((a).x+(b).x,(a).y+(b).y)
#define CSUB(a,b) make_float2((a).x-(b).x,(a).y-(b).y)
#define MULNI(t)  make_float2((t).y, -(t).x)
constexpr float C45 = 0.7071067811865476f;

__device__ __forceinline__ void fft8(float2* x) {
  float2 t;
  t = CSUB(x[0],x[4]); x[0]=CADD(x[0],x[4]); x[4]=t;
  t = CSUB(x[1],x[5]); x[1]=CADD(x[1],x[5]); x[5]=make_float2(C45*(t.x+t.y), C45*(t.y-t.x));
  t = CSUB(x[2],x[6]); x[2]=CADD(x[2],x[6]); x[6]=MULNI(t);
  t = CSUB(x[3],x[7]); x[3]=CADD(x[3],x[7]); x[7]=make_float2(C45*(t.y-t.x), -C45*(t.x+t.y));
  t = CSUB(x[0],x[2]); x[0]=CADD(x[0],x[2]); x[2]=t;
  t = CSUB(x[1],x[3]); x[1]=CADD(x[1],x[3]); x[3]=MULNI(t);
  t = CSUB(x[4],x[6]); x[4]=CADD(x[4],x[6]); x[6]=t;
  t = CSUB(x[5],x[7]); x[5]=CADD(x[5],x[7]); x[7]=MULNI(t);
  t = CSUB(x[0],x[1]); x[0]=CADD(x[0],x[1]); x[1]=t;
  t = CSUB(x[2],x[3]); x[2]=CADD(x[2],x[3]); x[3]=t;
  t = CSUB(x[4],x[5]); x[4]=CADD(x[4],x[5]); x[5]=t;
  t = CSUB(x[6],x[7]); x[6]=CADD(x[6],x[7]); x[7]=t;
}

__device__ __forceinline__ void fft16(float2* z) {
  float2 t;
  t=CSUB(z[0],z[8]);   z[0]=CADD(z[0],z[8]);   z[8]=t;
  t=CSUB(z[1],z[9]);   z[1]=CADD(z[1],z[9]);   z[9]=cmul(t,  make_float2( 0.9238795325f,-0.3826834324f));
  t=CSUB(z[2],z[10]);  z[2]=CADD(z[2],z[10]);  z[10]=make_float2(C45*(t.x+t.y), C45*(t.y-t.x));
  t=CSUB(z[3],z[11]);  z[3]=CADD(z[3],z[11]);  z[11]=cmul(t, make_float2( 0.3826834324f,-0.9238795325f));
  t=CSUB(z[4],z[12]);  z[4]=CADD(z[4],z[12]);  z[12]=MULNI(t);
  t=CSUB(z[5],z[13]);  z[5]=CADD(z[5],z[13]);  z[13]=cmul(t, make_float2(-0.3826834324f,-0.9238795325f));
  t=CSUB(z[6],z[14]);  z[6]=CADD(z[6],z[14]);  z[14]=make_float2(C45*(t.y-t.x), -C45*(t.x+t.y));
  t=CSUB(z[7],z[15]);  z[7]=CADD(z[7],z[15]);  z[15]=cmul(t, make_float2(-0.9238795325f,-0.3826834324f));
  t=CSUB(z[0],z[4]);   z[0]=CADD(z[0],z[4]);   z[4]=t;
  t=CSUB(z[1],z[5]);   z[1]=CADD(z[1],z[5]);   z[5]=make_float2(C45*(t.x+t.y), C45*(t.y-t.x));
  t=CSUB(z[2],z[6]);   z[2]=CADD(z[2],z[6]);   z[6]=MULNI(t);
  t=CSUB(z[3],z[7]);   z[3]=CADD(z[3],z[7]);   z[7]=make_float2(C45*(t.y-t.x), -C45*(t.x+t.y));
  t=CSUB(z[8],z[12]);  z[8]=CADD(z[8],z[12]);  z[12]=t;
  t=CSUB(z[9],z[13]);  z[9]=CADD(z[9],z[13]);  z[13]=make_float2(C45*(t.x+t.y), C45*(t.y-t.x));
  t=CSUB(z[10],z[14]); z[10]=CADD(z[10],z[14]); z[14]=MULNI(t);
  t=CSUB(z[11],z[15]); z[11]=CADD(z[11],z[15]); z[15]=make_float2(C45*(t.y-t.x), -C45*(t.x+t.y));
  t=CSUB(z[0],z[2]);   z[0]=CADD(z[0],z[2]);   z[2]=t;
  t=CSUB(z[1],z[3]);   z[1]=CADD(z[1],z[3]);   z[3]=MULNI(t);
  t=CSUB(z[4],z[6]);   z[4]=CADD(z[4],z[6]);   z[6]=t;
  t=CSUB(z[5],z[7]);   z[5]=CADD(z[5],z[7]);   z[7]=MULNI(t);
  t=CSUB(z[8],z[10]);  z[8]=CADD(z[8],z[10]);  z[10]=t;
  t=CSUB(z[9],z[11]);  z[9]=CADD(z[9],z[11]);  z[11]=MULNI(t);
  t=CSUB(z[12],z[14]); z[12]=CADD(z[12],z[14]); z[14]=t;
  t=CSUB(z[13],z[15]); z[13]=CADD(z[13],z[15]); z[15]=MULNI(t);
  t=CSUB(z[0],z[1]);   z[0]=CADD(z[0],z[1]);   z[1]=t;
  t=CSUB(z[2],z[3]);   z[2]=CADD(z[2],z[3]);   z[3]=t;
  t=CSUB(z[4],z[5]);   z[4]=CADD(z[4],z[5]);   z[5]=t;
  t=CSUB(z[6],z[7]);   z[6]=CADD(z[6],z[7]);   z[7]=t;
  t=CSUB(z[8],z[9]);   z[8]=CADD(z[8],z[9]);   z[9]=t;
  t=CSUB(z[10],z[11]); z[10]=CADD(z[10],z[11]); z[11]=t;
  t=CSUB(z[12],z[13]); z[12]=CADD(z[12],z[13]); z[13]=t;
  t=CSUB(z[14],z[15]); z[14]=CADD(z[14],z[15]); z[15]=t;
}

// EPI==1: final write applies exp(x*escale), accumulates lane-sum.
template<int SPT, int SLN, int EPI>
__device__ __forceinline__ void fft_pass(float2* img, const float2* tw,
                                         int lane, int wid,
                                         float escale, float& lsum) {
  const int n2 = lane & 15, rr = lane >> 4;
  constexpr int br3[8] = {0,4,2,6,1,5,3,7};
#pragma unroll
  for (int u = 0; u < 2; ++u) {
    const int lb = SLN * (wid * 8 + u * 4 + rr);
    float2 x[8];
#pragma unroll
    for (int n1 = 0; n1 < 8; ++n1) x[n1] = img[lb + SPT * (16 * n1 + n2)];
    fft8(x);
#pragma unroll
    for (int m = 0; m < 8; ++m) {
      const int k1 = br3[m];
      const float2 y = (k1 == 0) ? x[m] : cmul(x[m], tw[k1 - 1]);
      img[lb + SPT * (16 * k1 + (n2 ^ k1))] = y;
    }
  }
  const int k1 = lane & 7;
  const int lb = SLN * (wid * 8 + (lane >> 3));
  const int kb = 16 * k1;
  float2 z[16];
#pragma unroll
  for (int j = 0; j < 16; ++j) z[j] = img[lb + SPT * (kb + (j ^ k1))];
  fft16(z);
  constexpr int br4[16] = {0,8,4,12,2,10,6,14,1,9,5,13,3,11,7,15};
#pragma unroll
  for (int m = 0; m < 16; ++m) {
    const int a = lb + SPT * (k1 + 8 * br4[m]);
    if (EPI == 1) {
      const float ex = __expf(z[m].x * escale);
      lsum += ex;
      img[a] = make_float2(ex, 0.0f);
    } else {
      img[a] = z[m];
    }
  }
}

template<int EPI>
__device__ __forceinline__ void fft2d(float2* img, const float2* tw,
                                      int lane, int wid, float escale, float& lsum) {
  float dummy = 0.0f;
  fft_pass<1, RS, 0>(img, tw, lane, wid, 0.0f, dummy);
  __syncthreads();
  fft_pass<RS, 1, EPI>(img, tw, lane, wid, escale, lsum);
  __syncthreads();
}

__device__ __forceinline__ void cross_spectrum(float2* img, int tid) {
  for (int idx = tid; idx < NSP; idx += NT) {
    const int fr = idx >> 7, fc = idx & 127;
    const int gr = (128 - fr) & 127, gc = (128 - fc) & 127;
    const int gidx = (gr << 7) | gc;
    if (idx > gidx) continue;
    const int f = fr * RS + fc;
    const float2 zf = img[f];
    if (idx == gidx) {
      img[f] = make_float2(zf.x * zf.y, 0.0f);
    } else {
      const int g = gr * RS + gc;
      const float2 zg = img[g];
      const float qr = 0.5f * (zf.x + zg.x), qi = 0.5f * (zf.y - zg.y);
      const float kr = 0.5f * (zf.y + zg.y), ki = 0.5f * (zg.x - zf.x);
      const float yr = qr * kr + qi * ki;
      const float yi = qr * ki - qi * kr;
      img[f] = make_float2(yr, -yi);
      img[g] = make_float2(yr, yi);
    }
  }
}

__global__ __launch_bounds__(NT)
void fft_attn_fused(const float* __restrict__ Qin, const float* __restrict__ Kin,
                    const float* __restrict__ Vin, float* __restrict__ Out) {
  __shared__ float2 img[128 * RS];
  __shared__ float red[NW];
  const int tid = threadIdx.x, lane = tid & 63, wid = tid >> 6;
  const size_t off = (size_t)blockIdx.x * NSP;

  // prefetch V (used after softmax; loads stay in flight / in regs)
  float4 vpre[4];
#pragma unroll
  for (int i = 0; i < 4; ++i)
    vpre[i] = *(const float4*)(Vin + off + (tid + i * NT) * 4);

  float2 tw[7];
  {
    const int n2 = lane & 15;
#pragma unroll
    for (int k = 1; k < 8; ++k) {
      float s, c;
      sincosf(6.283185307179586f * (float)(n2 * k) * (1.0f / 128.0f), &s, &c);
      tw[k - 1] = make_float2(c, -s);
    }
  }

  // pack z = Q + i*K
#pragma unroll
  for (int i = 0; i < 4; ++i) {
    const int e = (tid + i * NT) * 4;
    const float4 q4 = *(const float4*)(Qin + off + e);
    const float4 k4 = *(const float4*)(Kin + off + e);
    float2* p = img + (e >> 7) * RS + (e & 127);
    p[0] = make_float2(q4.x, k4.x); p[1] = make_float2(q4.y, k4.y);
    p[2] = make_float2(q4.z, k4.z); p[3] = make_float2(q4.w, k4.w);
  }
  __syncthreads();

  // ---- stage 1: corr(Q,K) + fused exp ----
  float dummy = 0.0f;
  fft2d<0>(img, tw, lane, wid, 0.0f, dummy);
  cross_spectrum(img, tid);
  __syncthreads();
  const float escale = 1.0f / 2097152.0f;    // N^{-3/2}; |logit| ~ O(1), no max-sub
  float lsum = 0.0f;
  fft2d<1>(img, tw, lane, wid, escale, lsum);  // img.x = exp(logit)

  // block-reduce sum of exp
#pragma unroll
  for (int s = 32; s >= 1; s >>= 1) lsum += __shfl_xor(lsum, s, 64);
  if (lane == 0) red[wid] = lsum;
  __syncthreads();
  float tot = 0.0f;
#pragma unroll
  for (int w = 0; w < NW; ++w) tot += red[w];
  const float inv = 1.0f / tot;              // folded into final scale

  // pack .y = V (exp stays un-normalized in .x)
#pragma unroll
  for (int i = 0; i < 4; ++i) {
    const int e = (tid + i * NT) * 4;
    float2* p = img + (e >> 7) * RS + (e & 127);
    p[0].y = vpre[i].x; p[1].y = vpre[i].y;
    p[2].y = vpre[i].z; p[3].y = vpre[i].w;
  }
  __syncthreads();

  // ---- stage 2: corr(exp, V) * inv/N ----
  fft2d<0>(img, tw, lane, wid, 0.0f, dummy);
  cross_spectrum(img, tid);
  __syncthreads();
  fft2d<0>(img, tw, lane, wid, 0.0f, dummy);

  const float os = inv * (1.0f / 16384.0f);
#pragma unroll
  for (int i = 0; i < 4; ++i) {
    const int e = (tid + i * NT) * 4;
    float2* p = img + (e >> 7) * RS + (e & 127);
    float4 o;
    o.x = p[0].x * os; o.y = p[1].x * os; o.z = p[2].x * os; o.w = p[3].x * os;
    *(float4*)(Out + off + e) = o;
  }
}

// ---------------- launch ----------------

extern "C" void kernel_launch(void* const* d_in, const int* in_sizes, int n_in,
                              void* d_out, int out_size, void* d_ws, size_t ws_size,
                              hipStream_t stream) {
  const float* x      = (const float*)d_in[0];
  const float* w_qkv  = (const float*)d_in[1];
  const float* w_gate = (const float*)d_in[2];
  const float* b_gate = (const float*)d_in[3];
  const float* w_proj = (const float*)d_in[4];
  const float* b_proj = (const float*)d_in[5];
  float* outp = (float*)d_out;

  const size_t SZ = (size_t)BATCH * CH * NSP;
  float* Q = (float*)d_ws;   // also receives corr(exp, V) in-place
  float* K = Q + SZ;
  float* V = K + SZ;
  float* T = V + SZ;

  dim3 g1(128, BATCH);
  gemm_qkvg<<<g1, 256, 0, stream>>>(x, w_qkv, w_gate, b_gate, Q, K, V, T);

  fft_attn_fused<<<NIMG, NT, 0, stream>>>(Q, K, V, Q);

  dim3 g2(128, BATCH);
  gemm_proj<<<g2, 256, 0, stream>>>(Q, T, w_proj, b_proj, outp);
}

// Round 6
// 442.430 us; speedup vs baseline: 2.0171x; 1.0259x over previous
//
#include <hip/hip_runtime.h>
#include <math.h>

// CirculantAttention on MI355X.
//   attn = softmax_n( N^{-3/2} * circ_corr(Xq, Xk) )   per (b,c) image
//   out  = (1/N)    *  circ_corr(attn, Xv)
// GEMMs in spatial domain via bf16x3-split MFMA. FFT: 8x16 two-phase
// in-register engine; exp fused into inverse col pass; softmax normalization
// folded into final scale. V loaded late (L3-resident from gemm_qkvg).

constexpr int CH    = 128;
constexpr int NSP   = 128 * 128;   // 16384
constexpr int BATCH = 8;
constexpr int NIMG  = BATCH * CH;  // 1024
constexpr int RS    = 130;         // fft complex row stride
constexpr int NT    = 1024;        // fft threads (16 waves)
constexpr int NW    = NT / 64;

// ======================= MFMA GEMM machinery =======================

typedef short short8 __attribute__((ext_vector_type(8)));
typedef float f32x4  __attribute__((ext_vector_type(4)));
union U8 { unsigned u[4]; short8 s; };

__device__ __forceinline__ unsigned bf16r(float x) {   // RNE -> low 16 bits
  unsigned u = __float_as_uint(x);
  return (u + 0x7FFFu + ((u >> 16) & 1u)) >> 16;
}

__device__ __forceinline__ void split_pair(float e0, float e1,
                                           unsigned& hi, unsigned& lo) {
  const unsigned u0 = __float_as_uint(e0), u1 = __float_as_uint(e1);
  hi = (u0 >> 16) | (u1 & 0xFFFF0000u);
  const float r0 = e0 - __uint_as_float(u0 & 0xFFFF0000u);
  const float r1 = e1 - __uint_as_float(u1 & 0xFFFF0000u);
  lo = bf16r(r0) | (bf16r(r1) << 16);
}

__device__ __forceinline__ void load_a_frag(const float* wr, short8& ah, short8& al) {
  const float4 wa = *(const float4*)wr;
  const float4 wb = *(const float4*)(wr + 4);
  U8 hi, lo;
  split_pair(wa.x, wa.y, hi.u[0], lo.u[0]);
  split_pair(wa.z, wa.w, hi.u[1], lo.u[1]);
  split_pair(wb.x, wb.y, hi.u[2], lo.u[2]);
  split_pair(wb.z, wb.w, hi.u[3], lo.u[3]);
  ah = hi.s; al = lo.s;
}

// xs: bf16 hi plane [0,8192), lo plane [8192,16384), XOR-swizzled words.
__device__ __forceinline__ void mfma_core(const unsigned* xs, const float* wbase,
                                          f32x4 acc[4][4], int tid) {
  const int lane = tid & 63, wid = tid >> 6;
  const int mb = (wid >> 1) * 64;
  const int nb = (wid & 1) * 64;
  const int lm = lane & 15, quad = lane >> 4;
#pragma unroll
  for (int kg = 0; kg < 4; ++kg) {
    short8 ah[4], al[4], bh[4], bl[4];
#pragma unroll
    for (int mf = 0; mf < 4; ++mf) {
      const float* wr = wbase + (size_t)(mb + mf * 16 + lm) * CH + kg * 32 + quad * 8;
      load_a_frag(wr, ah[mf], al[mf]);
    }
    const int kwb = (kg * 16 + quad * 4) ^ (lm << 2);
#pragma unroll
    for (int nf = 0; nf < 4; ++nf) {
      const unsigned* p = xs + (nb + nf * 16 + lm) * 64 + kwb;
      bh[nf] = *(const short8*)p;
      bl[nf] = *(const short8*)(p + 8192);
    }
#pragma unroll
    for (int mf = 0; mf < 4; ++mf)
#pragma unroll
      for (int nf = 0; nf < 4; ++nf)
        acc[mf][nf] = __builtin_amdgcn_mfma_f32_16x16x32_bf16(al[mf], bh[nf], acc[mf][nf], 0, 0, 0);
#pragma unroll
    for (int mf = 0; mf < 4; ++mf)
#pragma unroll
      for (int nf = 0; nf < 4; ++nf)
        acc[mf][nf] = __builtin_amdgcn_mfma_f32_16x16x32_bf16(ah[mf], bl[nf], acc[mf][nf], 0, 0, 0);
#pragma unroll
    for (int mf = 0; mf < 4; ++mf)
#pragma unroll
      for (int nf = 0; nf < 4; ++nf)
        acc[mf][nf] = __builtin_amdgcn_mfma_f32_16x16x32_bf16(ah[mf], bh[nf], acc[mf][nf], 0, 0, 0);
  }
}

// ---------------- GEMM 1: one block -> Q,K,V,T for one (b, n-tile) ----------------
// X staged once (64 KB); per-wave private 2 KB LDS mini-bounce makes every
// global store a 128 B-aligned float4 run. No barriers in the epilogue.

__global__ __launch_bounds__(256, 2)
void gemm_qkvg(const float* __restrict__ x, const float* __restrict__ w_qkv,
               const float* __restrict__ w_gate, const float* __restrict__ b_gate,
               float* __restrict__ Q, float* __restrict__ K,
               float* __restrict__ V, float* __restrict__ T) {
  __shared__ __align__(16) unsigned xs[16384];      // 64 KB
  __shared__ __align__(16) float bounce[4 * 528];   // 16x33 per wave, 8.4 KB
  const int tid = threadIdx.x;
  const int n0 = blockIdx.x * 128;
  const int b  = blockIdx.y;
  const float* xb = x + (size_t)b * CH * NSP;

  {
    const int tn = tid >> 3;
    const int tk = tid & 7;
#pragma unroll
    for (int i = 0; i < 8; ++i) {
      const int k = 2 * tk + 16 * i;
      const float* p0 = xb + (size_t)k * NSP + n0 + 4 * tn;
      const float4 a = *(const float4*)p0;
      const float4 c = *(const float4*)(p0 + NSP);
      const float a4[4] = {a.x, a.y, a.z, a.w};
      const float c4[4] = {c.x, c.y, c.z, c.w};
      const int kw = tk + 8 * i;
#pragma unroll
      for (int j = 0; j < 4; ++j) {
        const int nn = 4 * tn + j;
        unsigned hi, lo;
        split_pair(a4[j], c4[j], hi, lo);
        const int kws = kw ^ ((nn & 15) << 2);
        xs[nn * 64 + kws] = hi;
        xs[8192 + nn * 64 + kws] = lo;
      }
    }
  }
  __syncthreads();

  const int lane = tid & 63, wid = tid >> 6;
  const int mb = (wid >> 1) * 64, nb = (wid & 1) * 64;
  const int lm = lane & 15, quad = lane >> 4;
  float* const bw = bounce + wid * 528;
  float* const targs[4] = {Q, K, V, T};

#pragma unroll 1
  for (int dsel = 0; dsel < 4; ++dsel) {
    const float* wbase = (dsel == 3) ? w_gate : (w_qkv + (size_t)dsel * CH * CH);
    f32x4 acc[4][4];
#pragma unroll
    for (int mf = 0; mf < 4; ++mf)
#pragma unroll
      for (int nf = 0; nf < 4; ++nf) acc[mf][nf] = (f32x4){0.f, 0.f, 0.f, 0.f};

    mfma_core(xs, wbase, acc, tid);

    float* targ = targs[dsel];
#pragma unroll
    for (int mf = 0; mf < 4; ++mf) {
#pragma unroll
      for (int half = 0; half < 2; ++half) {
        // scatter 16 rows x 32 cols of this fragment into the private bounce
#pragma unroll
        for (int nn = 0; nn < 2; ++nn) {
          const int nf = half * 2 + nn;
#pragma unroll
          for (int i = 0; i < 4; ++i)
            bw[(quad * 4 + i) * 33 + nn * 16 + lm] = acc[mf][nf][i];
        }
        // read back row-major, store coalesced 128 B runs
#pragma unroll
        for (int j = 0; j < 2; ++j) {
          const int rl = (lane >> 3) + 8 * j;
          const int cl = (lane & 7) * 4;
          float4 v = *(const float4*)(bw + rl * 33 + cl);
          const int row = mb + mf * 16 + rl;
          if (dsel == 3) {
            const float bg = b_gate[row];
            float e[4] = {v.x, v.y, v.z, v.w};
#pragma unroll
            for (int q = 0; q < 4; ++q) {
              const float g = e[q] + bg;
              e[q] = g / (1.0f + __expf(-g));
            }
            v = make_float4(e[0], e[1], e[2], e[3]);
          }
          *(float4*)(targ + ((size_t)b * CH + row) * NSP + n0 + nb + half * 32 + cl) = v;
        }
      }
    }
  }
}

// ---------------- GEMM 2: w_proj @ (oc .* t) + b_proj ----------------

__device__ __forceinline__ void acc_to_bounce(float* bounce, f32x4 acc[4][4], int tid) {
  const int lane = tid & 63, wid = tid >> 6;
  const int mb = (wid >> 1) * 64;
  const int nb = (wid & 1) * 64;
  const int lm = lane & 15, quad = lane >> 4;
#pragma unroll
  for (int mf = 0; mf < 4; ++mf)
#pragma unroll
    for (int nf = 0; nf < 4; ++nf) {
      const int col = nb + nf * 16 + lm;
      const int r0 = mb + mf * 16 + quad * 4;
#pragma unroll
      for (int i = 0; i < 4; ++i)
        bounce[(r0 + i) * 132 + col] = acc[mf][nf][i];
    }
}

__global__ __launch_bounds__(256, 2)
void gemm_proj(const float* __restrict__ OC, const float* __restrict__ Tn,
               const float* __restrict__ w_proj, const float* __restrict__ b_proj,
               float* __restrict__ outp) {
  __shared__ __align__(16) unsigned xs[16896];
  const int tid = threadIdx.x;
  const int n0 = blockIdx.x * 128;
  const int b = blockIdx.y;
  const float* ob = OC + (size_t)b * CH * NSP;
  const float* tb = Tn + (size_t)b * CH * NSP;

  {
    const int tn = tid >> 3;
    const int tk = tid & 7;
#pragma unroll
    for (int i = 0; i < 8; ++i) {
      const int k = 2 * tk + 16 * i;
      const float* po = ob + (size_t)k * NSP + n0 + 4 * tn;
      const float* pt = tb + (size_t)k * NSP + n0 + 4 * tn;
      const float4 o0 = *(const float4*)po;
      const float4 o1 = *(const float4*)(po + NSP);
      const float4 t0 = *(const float4*)pt;
      const float4 t1 = *(const float4*)(pt + NSP);
      const float z0[4] = {o0.x * t0.x, o0.y * t0.y, o0.z * t0.z, o0.w * t0.w};
      const float z1[4] = {o1.x * t1.x, o1.y * t1.y, o1.z * t1.z, o1.w * t1.w};
      const int kw = tk + 8 * i;
#pragma unroll
      for (int j = 0; j < 4; ++j) {
        const int nn = 4 * tn + j;
        unsigned hi, lo;
        split_pair(z0[j], z1[j], hi, lo);
        const int kws = kw ^ ((nn & 15) << 2);
        xs[nn * 64 + kws] = hi;
        xs[8192 + nn * 64 + kws] = lo;
      }
    }
  }
  __syncthreads();

  f32x4 acc[4][4];
#pragma unroll
  for (int mf = 0; mf < 4; ++mf)
#pragma unroll
    for (int nf = 0; nf < 4; ++nf) acc[mf][nf] = (f32x4){0.f, 0.f, 0.f, 0.f};

  mfma_core(xs, w_proj, acc, tid);

  __syncthreads();
  float* bounce = (float*)xs;
  acc_to_bounce(bounce, acc, tid);
  __syncthreads();

  const int rr = tid >> 5;
  const int c4i = (tid & 31) * 4;
#pragma unroll
  for (int i = 0; i < 16; ++i) {
    const int row = rr + 8 * i;
    const float bp = b_proj[row];
    float4 v = *(const float4*)(bounce + row * 132 + c4i);
    v.x += bp; v.y += bp; v.z += bp; v.w += bp;
    *(float4*)(outp + ((size_t)b * CH + row) * NSP + n0 + c4i) = v;
  }
}

// ======================= FFT attention =======================

__device__ __forceinline__ float2 cmul(float2 a, float2 b) {
  return make_float2(fmaf(a.x, b.x, -(a.y * b.y)), fmaf(a.x, b.y, a.y * b.x));
}
#define CADD(a,b) make_float2((a).x+(b).x,(a).y+(b).y)
#define CSUB(a,b) make_float2((a).x-(b).x,(a).y-(b).y)
#define MULNI(t)  make_float2((t).y, -(t).x)
constexpr float C45 = 0.7071067811865476f;

__device__ __forceinline__ void fft8(float2* x) {
  float2 t;
  t = CSUB(x[0],x[4]); x[0]=CADD(x[0],x[4]); x[4]=t;
  t = CSUB(x[1],x[5]); x[1]=CADD(x[1],x[5]); x[5]=make_float2(C45*(t.x+t.y), C45*(t.y-t.x));
  t = CSUB(x[2],x[6]); x[2]=CADD(x[2],x[6]); x[6]=MULNI(t);
  t = CSUB(x[3],x[7]); x[3]=CADD(x[3],x[7]); x[7]=make_float2(C45*(t.y-t.x), -C45*(t.x+t.y));
  t = CSUB(x[0],x[2]); x[0]=CADD(x[0],x[2]); x[2]=t;
  t = CSUB(x[1],x[3]); x[1]=CADD(x[1],x[3]); x[3]=MULNI(t);
  t = CSUB(x[4],x[6]); x[4]=CADD(x[4],x[6]); x[6]=t;
  t = CSUB(x[5],x[7]); x[5]=CADD(x[5],x[7]); x[7]=MULNI(t);
  t = CSUB(x[0],x[1]); x[0]=CADD(x[0],x[1]); x[1]=t;
  t = CSUB(x[2],x[3]); x[2]=CADD(x[2],x[3]); x[3]=t;
  t = CSUB(x[4],x[5]); x[4]=CADD(x[4],x[5]); x[5]=t;
  t = CSUB(x[6],x[7]); x[6]=CADD(x[6],x[7]); x[7]=t;
}

__device__ __forceinline__ void fft16(float2* z) {
  float2 t;
  t=CSUB(z[0],z[8]);   z[0]=CADD(z[0],z[8]);   z[8]=t;
  t=CSUB(z[1],z[9]);   z[1]=CADD(z[1],z[9]);   z[9]=cmul(t,  make_float2( 0.9238795325f,-0.3826834324f));
  t=CSUB(z[2],z[10]);  z[2]=CADD(z[2],z[10]);  z[10]=make_float2(C45*(t.x+t.y), C45*(t.y-t.x));
  t=CSUB(z[3],z[11]);  z[3]=CADD(z[3],z[11]);  z[11]=cmul(t, make_float2( 0.3826834324f,-0.9238795325f));
  t=CSUB(z[4],z[12]);  z[4]=CADD(z[4],z[12]);  z[12]=MULNI(t);
  t=CSUB(z[5],z[13]);  z[5]=CADD(z[5],z[13]);  z[13]=cmul(t, make_float2(-0.3826834324f,-0.9238795325f));
  t=CSUB(z[6],z[14]);  z[6]=CADD(z[6],z[14]);  z[14]=make_float2(C45*(t.y-t.x), -C45*(t.x+t.y));
  t=CSUB(z[7],z[15]);  z[7]=CADD(z[7],z[15]);  z[15]=cmul(t, make_float2(-0.9238795325f,-0.3826834324f));
  t=CSUB(z[0],z[4]);   z[0]=CADD(z[0],z[4]);   z[4]=t;
  t=CSUB(z[1],z[5]);   z[1]=CADD(z[1],z[5]);   z[5]=make_float2(C45*(t.x+t.y), C45*(t.y-t.x));
  t=CSUB(z[2],z[6]);   z[2]=CADD(z[2],z[6]);   z[6]=MULNI(t);
  t=CSUB(z[3],z[7]);   z[3]=CADD(z[3],z[7]);   z[7]=make_float2(C45*(t.y-t.x), -C45*(t.x+t.y));
  t=CSUB(z[8],z[12]);  z[8]=CADD(z[8],z[12]);  z[12]=t;
  t=CSUB(z[9],z[13]);  z[9]=CADD(z[9],z[13]);  z[13]=make_float2(C45*(t.x+t.y), C45*(t.y-t.x));
  t=CSUB(z[10],z[14]); z[10]=CADD(z[10],z[14]); z[14]=MULNI(t);
  t=CSUB(z[11],z[15]); z[11]=CADD(z[11],z[15]); z[15]=make_float2(C45*(t.y-t.x), -C45*(t.x+t.y));
  t=CSUB(z[0],z[2]);   z[0]=CADD(z[0],z[2]);   z[2]=t;
  t=CSUB(z[1],z[3]);   z[1]=CADD(z[1],z[3]);   z[3]=MULNI(t);
  t=CSUB(z[4],z[6]);   z[4]=CADD(z[4],z[6]);   z[6]=t;
  t=CSUB(z[5],z[7]);   z[5]=CADD(z[5],z[7]);   z[7]=MULNI(t);
  t=CSUB(z[8],z[10]);  z[8]=CADD(z[8],z[10]);  z[10]=t;
  t=CSUB(z[9],z[11]);  z[9]=CADD(z[9],z[11]);  z[11]=MULNI(t);
  t=CSUB(z[12],z[14]); z[12]=CADD(z[12],z[14]); z[14]=t;
  t=CSUB(z[13],z[15]); z[13]=CADD(z[13],z[15]); z[15]=MULNI(t);
  t=CSUB(z[0],z[1]);   z[0]=CADD(z[0],z[1]);   z[1]=t;
  t=CSUB(z[2],z[3]);   z[2]=CADD(z[2],z[3]);   z[3]=t;
  t=CSUB(z[4],z[5]);   z[4]=CADD(z[4],z[5]);   z[5]=t;
  t=CSUB(z[6],z[7]);   z[6]=CADD(z[6],z[7]);   z[7]=t;
  t=CSUB(z[8],z[9]);   z[8]=CADD(z[8],z[9]);   z[9]=t;
  t=CSUB(z[10],z[11]); z[10]=CADD(z[10],z[11]); z[11]=t;
  t=CSUB(z[12],z[13]); z[12]=CADD(z[12],z[13]); z[13]=t;
  t=CSUB(z[14],z[15]); z[14]=CADD(z[14],z[15]); z[15]=t;
}

// EPI==1: final write applies exp(x*escale), accumulates lane-sum.
template<int SPT, int SLN, int EPI>
__device__ __forceinline__ void fft_pass(float2* img, const float2* tw,
                                         int lane, int wid,
                                         float escale, float& lsum) {
  const int n2 = lane & 15, rr = lane >> 4;
  constexpr int br3[8] = {0,4,2,6,1,5,3,7};
#pragma unroll
  for (int u = 0; u < 2; ++u) {
    const int lb = SLN * (wid * 8 + u * 4 + rr);
    float2 x[8];
#pragma unroll
    for (int n1 = 0; n1 < 8; ++n1) x[n1] = img[lb + SPT * (16 * n1 + n2)];
    fft8(x);
#pragma unroll
    for (int m = 0; m < 8; ++m) {
      const int k1 = br3[m];
      const float2 y = (k1 == 0) ? x[m] : cmul(x[m], tw[k1 - 1]);
      img[lb + SPT * (16 * k1 + (n2 ^ k1))] = y;
    }
  }
  const int k1 = lane & 7;
  const int lb = SLN * (wid * 8 + (lane >> 3));
  const int kb = 16 * k1;
  float2 z[16];
#pragma unroll
  for (int j = 0; j < 16; ++j) z[j] = img[lb + SPT * (kb + (j ^ k1))];
  fft16(z);
  constexpr int br4[16] = {0,8,4,12,2,10,6,14,1,9,5,13,3,11,7,15};
#pragma unroll
  for (int m = 0; m < 16; ++m) {
    const int a = lb + SPT * (k1 + 8 * br4[m]);
    if (EPI == 1) {
      const float ex = __expf(z[m].x * escale);
      lsum += ex;
      img[a] = make_float2(ex, 0.0f);
    } else {
      img[a] = z[m];
    }
  }
}

template<int EPI>
__device__ __forceinline__ void fft2d(float2* img, const float2* tw,
                                      int lane, int wid, float escale, float& lsum) {
  float dummy = 0.0f;
  fft_pass<1, RS, 0>(img, tw, lane, wid, 0.0f, dummy);
  __syncthreads();
  fft_pass<RS, 1, EPI>(img, tw, lane, wid, escale, lsum);
  __syncthreads();
}

__device__ __forceinline__ void cross_spectrum(float2* img, int tid) {
  for (int idx = tid; idx < NSP; idx += NT) {
    const int fr = idx >> 7, fc = idx & 127;
    const int gr = (128 - fr) & 127, gc = (128 - fc) & 127;
    const int gidx = (gr << 7) | gc;
    if (idx > gidx) continue;
    const int f = fr * RS + fc;
    const float2 zf = img[f];
    if (idx == gidx) {
      img[f] = make_float2(zf.x * zf.y, 0.0f);
    } else {
      const int g = gr * RS + gc;
      const float2 zg = img[g];
      const float qr = 0.5f * (zf.x + zg.x), qi = 0.5f * (zf.y - zg.y);
      const float kr = 0.5f * (zf.y + zg.y), ki = 0.5f * (zg.x - zf.x);
      const float yr = qr * kr + qi * ki;
      const float yi = qr * ki - qi * kr;
      img[f] = make_float2(yr, -yi);
      img[g] = make_float2(yr, yi);
    }
  }
}

__global__ __launch_bounds__(NT)
void fft_attn_fused(const float* __restrict__ Qin, const float* __restrict__ Kin,
                    const float* __restrict__ Vin, float* __restrict__ Out) {
  __shared__ float2 img[128 * RS];
  __shared__ float red[NW];
  const int tid = threadIdx.x, lane = tid & 63, wid = tid >> 6;
  const size_t off = (size_t)blockIdx.x * NSP;

  float2 tw[7];
  {
    const int n2 = lane & 15;
#pragma unroll
    for (int k = 1; k < 8; ++k) {
      float s, c;
      sincosf(6.283185307179586f * (float)(n2 * k) * (1.0f / 128.0f), &s, &c);
      tw[k - 1] = make_float2(c, -s);
    }
  }

  // pack z = Q + i*K
#pragma unroll
  for (int i = 0; i < 4; ++i) {
    const int e = (tid + i * NT) * 4;
    const float4 q4 = *(const float4*)(Qin + off + e);
    const float4 k4 = *(const float4*)(Kin + off + e);
    float2* p = img + (e >> 7) * RS + (e & 127);
    p[0] = make_float2(q4.x, k4.x); p[1] = make_float2(q4.y, k4.y);
    p[2] = make_float2(q4.z, k4.z); p[3] = make_float2(q4.w, k4.w);
  }
  __syncthreads();

  // ---- stage 1: corr(Q,K) + fused exp ----
  float dummy = 0.0f;
  fft2d<0>(img, tw, lane, wid, 0.0f, dummy);
  cross_spectrum(img, tid);
  __syncthreads();
  const float escale = 1.0f / 2097152.0f;    // N^{-3/2}; |logit| ~ O(1), no max-sub
  float lsum = 0.0f;
  fft2d<1>(img, tw, lane, wid, escale, lsum);  // img.x = exp(logit)

#pragma unroll
  for (int s = 32; s >= 1; s >>= 1) lsum += __shfl_xor(lsum, s, 64);
  if (lane == 0) red[wid] = lsum;
  __syncthreads();
  float tot = 0.0f;
#pragma unroll
  for (int w = 0; w < NW; ++w) tot += red[w];
  const float inv = 1.0f / tot;              // folded into final scale

  // pack .y = V (late load: V is L3-resident from gemm_qkvg)
#pragma unroll
  for (int i = 0; i < 4; ++i) {
    const int e = (tid + i * NT) * 4;
    const float4 v4 = *(const float4*)(Vin + off + e);
    float2* p = img + (e >> 7) * RS + (e & 127);
    p[0].y = v4.x; p[1].y = v4.y;
    p[2].y = v4.z; p[3].y = v4.w;
  }
  __syncthreads();

  // ---- stage 2: corr(exp, V) * inv/N ----
  fft2d<0>(img, tw, lane, wid, 0.0f, dummy);
  cross_spectrum(img, tid);
  __syncthreads();
  fft2d<0>(img, tw, lane, wid, 0.0f, dummy);

  const float os = inv * (1.0f / 16384.0f);
#pragma unroll
  for (int i = 0; i < 4; ++i) {
    const int e = (tid + i * NT) * 4;
    float2* p = img + (e >> 7) * RS + (e & 127);
    float4 o;
    o.x = p[0].x * os; o.y = p[1].x * os; o.z = p[2].x * os; o.w = p[3].x * os;
    *(float4*)(Out + off + e) = o;
  }
}

// ---------------- launch ----------------

extern "C" void kernel_launch(void* const* d_in, const int* in_sizes, int n_in,
                              void* d_out, int out_size, void* d_ws, size_t ws_size,
                              hipStream_t stream) {
  const float* x      = (const float*)d_in[0];
  const float* w_qkv  = (const float*)d_in[1];
  const float* w_gate = (const float*)d_in[2];
  const float* b_gate = (const float*)d_in[3];
  const float* w_proj = (const float*)d_in[4];
  const float* b_proj = (const float*)d_in[5];
  float* outp = (float*)d_out;

  const size_t SZ = (size_t)BATCH * CH * NSP;
  float* Q = (float*)d_ws;   // also receives corr(exp, V) in-place
  float* K = Q + SZ;
  float* V = K + SZ;
  float* T = V + SZ;

  dim3 g1(128, BATCH);
  gemm_qkvg<<<g1, 256, 0, stream>>>(x, w_qkv, w_gate, b_gate, Q, K, V, T);

  fft_attn_fused<<<NIMG, NT, 0, stream>>>(Q, K, V, Q);

  dim3 g2(128, BATCH);
  gemm_proj<<<g2, 256, 0, stream>>>(Q, T, w_proj, b_proj, outp);
}

// Round 7
// 435.196 us; speedup vs baseline: 2.0506x; 1.0166x over previous
//
#include <hip/hip_runtime.h>
#include <math.h>

// CirculantAttention on MI355X.
//   attn = softmax_n( N^{-3/2} * circ_corr(Xq, Xk) )   per (b,c) image
//   out  = (1/N)    *  circ_corr(attn, Xv)
// GEMMs in spatial domain via bf16x3-split MFMA. FFT: 8x16 two-phase
// in-register engine. Intermediates in bf16 (QK packed as one uint, V, oc);
// T (gate) stays fp32. FFT stage-1/2 row passes read QK / V directly from
// global (pack sweeps + 2 barriers eliminated).

constexpr int CH    = 128;
constexpr int NSP   = 128 * 128;   // 16384
constexpr int BATCH = 8;
constexpr int NIMG  = BATCH * CH;  // 1024
constexpr int RS    = 130;         // fft complex row stride
constexpr int NT    = 1024;        // fft threads (16 waves)
constexpr int NW    = NT / 64;

// ======================= MFMA GEMM machinery =======================

typedef short short8 __attribute__((ext_vector_type(8)));
typedef float f32x4  __attribute__((ext_vector_type(4)));
union U8 { unsigned u[4]; short8 s; };

__device__ __forceinline__ unsigned bf16r(float x) {   // RNE -> low 16 bits
  unsigned u = __float_as_uint(x);
  return (u + 0x7FFFu + ((u >> 16) & 1u)) >> 16;
}
__device__ __forceinline__ float bflo(unsigned w) { return __uint_as_float(w << 16); }
__device__ __forceinline__ float bfhi(unsigned w) { return __uint_as_float(w & 0xFFFF0000u); }

__device__ __forceinline__ void split_pair(float e0, float e1,
                                           unsigned& hi, unsigned& lo) {
  const unsigned u0 = __float_as_uint(e0), u1 = __float_as_uint(e1);
  hi = (u0 >> 16) | (u1 & 0xFFFF0000u);
  const float r0 = e0 - __uint_as_float(u0 & 0xFFFF0000u);
  const float r1 = e1 - __uint_as_float(u1 & 0xFFFF0000u);
  lo = bf16r(r0) | (bf16r(r1) << 16);
}

__device__ __forceinline__ void load_a_frag(const float* wr, short8& ah, short8& al) {
  const float4 wa = *(const float4*)wr;
  const float4 wb = *(const float4*)(wr + 4);
  U8 hi, lo;
  split_pair(wa.x, wa.y, hi.u[0], lo.u[0]);
  split_pair(wa.z, wa.w, hi.u[1], lo.u[1]);
  split_pair(wb.x, wb.y, hi.u[2], lo.u[2]);
  split_pair(wb.z, wb.w, hi.u[3], lo.u[3]);
  ah = hi.s; al = lo.s;
}

// xs: bf16 hi plane [0,8192), lo plane [8192,16384), XOR-swizzled words.
__device__ __forceinline__ void mfma_core(const unsigned* xs, const float* wbase,
                                          f32x4 acc[4][4], int tid) {
  const int lane = tid & 63, wid = tid >> 6;
  const int mb = (wid >> 1) * 64;
  const int nb = (wid & 1) * 64;
  const int lm = lane & 15, quad = lane >> 4;
#pragma unroll
  for (int kg = 0; kg < 4; ++kg) {
    short8 ah[4], al[4], bh[4], bl[4];
#pragma unroll
    for (int mf = 0; mf < 4; ++mf) {
      const float* wr = wbase + (size_t)(mb + mf * 16 + lm) * CH + kg * 32 + quad * 8;
      load_a_frag(wr, ah[mf], al[mf]);
    }
    const int kwb = (kg * 16 + quad * 4) ^ (lm << 2);
#pragma unroll
    for (int nf = 0; nf < 4; ++nf) {
      const unsigned* p = xs + (nb + nf * 16 + lm) * 64 + kwb;
      bh[nf] = *(const short8*)p;
      bl[nf] = *(const short8*)(p + 8192);
    }
#pragma unroll
    for (int mf = 0; mf < 4; ++mf)
#pragma unroll
      for (int nf = 0; nf < 4; ++nf)
        acc[mf][nf] = __builtin_amdgcn_mfma_f32_16x16x32_bf16(al[mf], bh[nf], acc[mf][nf], 0, 0, 0);
#pragma unroll
    for (int mf = 0; mf < 4; ++mf)
#pragma unroll
      for (int nf = 0; nf < 4; ++nf)
        acc[mf][nf] = __builtin_amdgcn_mfma_f32_16x16x32_bf16(ah[mf], bl[nf], acc[mf][nf], 0, 0, 0);
#pragma unroll
    for (int mf = 0; mf < 4; ++mf)
#pragma unroll
      for (int nf = 0; nf < 4; ++nf)
        acc[mf][nf] = __builtin_amdgcn_mfma_f32_16x16x32_bf16(ah[mf], bh[nf], acc[mf][nf], 0, 0, 0);
  }
}

// ---------------- GEMM 1: one block -> packed QK (bf16|bf16), V bf16, T fp32 ----------------

__global__ __launch_bounds__(256, 2)
void gemm_qkvg(const float* __restrict__ x, const float* __restrict__ w_qkv,
               const float* __restrict__ w_gate, const float* __restrict__ b_gate,
               unsigned* __restrict__ QKp, unsigned short* __restrict__ Vp,
               float* __restrict__ Tp) {
  __shared__ __align__(16) unsigned xs[16384];      // 64 KB
  __shared__ __align__(16) float bounce[4 * 528];   // 16x33 per wave
  const int tid = threadIdx.x;
  const int n0 = blockIdx.x * 128;
  const int b  = blockIdx.y;
  const float* xb = x + (size_t)b * CH * NSP;

  {
    const int tn = tid >> 3;
    const int tk = tid & 7;
#pragma unroll
    for (int i = 0; i < 8; ++i) {
      const int k = 2 * tk + 16 * i;
      const float* p0 = xb + (size_t)k * NSP + n0 + 4 * tn;
      const float4 a = *(const float4*)p0;
      const float4 c = *(const float4*)(p0 + NSP);
      const float a4[4] = {a.x, a.y, a.z, a.w};
      const float c4[4] = {c.x, c.y, c.z, c.w};
      const int kw = tk + 8 * i;
#pragma unroll
      for (int j = 0; j < 4; ++j) {
        const int nn = 4 * tn + j;
        unsigned hi, lo;
        split_pair(a4[j], c4[j], hi, lo);
        const int kws = kw ^ ((nn & 15) << 2);
        xs[nn * 64 + kws] = hi;
        xs[8192 + nn * 64 + kws] = lo;
      }
    }
  }
  __syncthreads();

  const int lane = tid & 63, wid = tid >> 6;
  const int mb = (wid >> 1) * 64, nb = (wid & 1) * 64;
  const int lm = lane & 15, quad = lane >> 4;
  float* const bw = bounce + wid * 528;
  unsigned* const ubw = (unsigned*)bw;

  // Q and K accs live simultaneously (packed write)
  f32x4 aq[4][4], ak[4][4];
#pragma unroll
  for (int mf = 0; mf < 4; ++mf)
#pragma unroll
    for (int nf = 0; nf < 4; ++nf) { aq[mf][nf] = (f32x4){0,0,0,0}; ak[mf][nf] = (f32x4){0,0,0,0}; }
  mfma_core(xs, w_qkv, aq, tid);
  mfma_core(xs, w_qkv + (size_t)CH * CH, ak, tid);

#pragma unroll
  for (int mf = 0; mf < 4; ++mf) {
#pragma unroll
    for (int half = 0; half < 2; ++half) {
#pragma unroll
      for (int nn = 0; nn < 2; ++nn) {
        const int nf = half * 2 + nn;
#pragma unroll
        for (int i = 0; i < 4; ++i)
          ubw[(quad * 4 + i) * 33 + nn * 16 + lm] =
              bf16r(aq[mf][nf][i]) | (bf16r(ak[mf][nf][i]) << 16);
      }
#pragma unroll
      for (int j = 0; j < 2; ++j) {
        const int rl = (lane >> 3) + 8 * j;
        const int cl = (lane & 7) * 4;
        const uint4 v = *(const uint4*)(ubw + rl * 33 + cl);
        const int row = mb + mf * 16 + rl;
        *(uint4*)(QKp + ((size_t)b * CH + row) * NSP + n0 + nb + half * 32 + cl) = v;
      }
    }
  }

  // V (bf16)
  f32x4 av[4][4];
#pragma unroll
  for (int mf = 0; mf < 4; ++mf)
#pragma unroll
    for (int nf = 0; nf < 4; ++nf) av[mf][nf] = (f32x4){0,0,0,0};
  mfma_core(xs, w_qkv + (size_t)2 * CH * CH, av, tid);
#pragma unroll
  for (int mf = 0; mf < 4; ++mf) {
#pragma unroll
    for (int half = 0; half < 2; ++half) {
#pragma unroll
      for (int nn = 0; nn < 2; ++nn) {
        const int nf = half * 2 + nn;
#pragma unroll
        for (int i = 0; i < 4; ++i)
          bw[(quad * 4 + i) * 33 + nn * 16 + lm] = av[mf][nf][i];
      }
#pragma unroll
      for (int j = 0; j < 2; ++j) {
        const int rl = (lane >> 3) + 8 * j;
        const int cl = (lane & 7) * 4;
        const float4 v = *(const float4*)(bw + rl * 33 + cl);
        const int row = mb + mf * 16 + rl;
        uint2 pv;
        pv.x = bf16r(v.x) | (bf16r(v.y) << 16);
        pv.y = bf16r(v.z) | (bf16r(v.w) << 16);
        *(uint2*)(Vp + ((size_t)b * CH + row) * NSP + n0 + nb + half * 32 + cl) = pv;
      }
    }
  }

  // T (silu, fp32)
  f32x4 at[4][4];
#pragma unroll
  for (int mf = 0; mf < 4; ++mf)
#pragma unroll
    for (int nf = 0; nf < 4; ++nf) at[mf][nf] = (f32x4){0,0,0,0};
  mfma_core(xs, w_gate, at, tid);
#pragma unroll
  for (int mf = 0; mf < 4; ++mf) {
#pragma unroll
    for (int half = 0; half < 2; ++half) {
#pragma unroll
      for (int nn = 0; nn < 2; ++nn) {
        const int nf = half * 2 + nn;
#pragma unroll
        for (int i = 0; i < 4; ++i)
          bw[(quad * 4 + i) * 33 + nn * 16 + lm] = at[mf][nf][i];
      }
#pragma unroll
      for (int j = 0; j < 2; ++j) {
        const int rl = (lane >> 3) + 8 * j;
        const int cl = (lane & 7) * 4;
        float4 v = *(const float4*)(bw + rl * 33 + cl);
        const int row = mb + mf * 16 + rl;
        const float bg = b_gate[row];
        float e[4] = {v.x, v.y, v.z, v.w};
#pragma unroll
        for (int q = 0; q < 4; ++q) {
          const float g = e[q] + bg;
          e[q] = g / (1.0f + __expf(-g));
        }
        v = make_float4(e[0], e[1], e[2], e[3]);
        *(float4*)(Tp + ((size_t)b * CH + row) * NSP + n0 + nb + half * 32 + cl) = v;
      }
    }
  }
}

// ---------------- GEMM 2: w_proj @ (oc_bf16 .* t) + b_proj -> fp32 out ----------------

__device__ __forceinline__ void acc_to_bounce(float* bounce, f32x4 acc[4][4], int tid) {
  const int lane = tid & 63, wid = tid >> 6;
  const int mb = (wid >> 1) * 64;
  const int nb = (wid & 1) * 64;
  const int lm = lane & 15, quad = lane >> 4;
#pragma unroll
  for (int mf = 0; mf < 4; ++mf)
#pragma unroll
    for (int nf = 0; nf < 4; ++nf) {
      const int col = nb + nf * 16 + lm;
      const int r0 = mb + mf * 16 + quad * 4;
#pragma unroll
      for (int i = 0; i < 4; ++i)
        bounce[(r0 + i) * 132 + col] = acc[mf][nf][i];
    }
}

__global__ __launch_bounds__(256, 2)
void gemm_proj(const unsigned short* __restrict__ OC, const float* __restrict__ Tn,
               const float* __restrict__ w_proj, const float* __restrict__ b_proj,
               float* __restrict__ outp) {
  __shared__ __align__(16) unsigned xs[16896];
  const int tid = threadIdx.x;
  const int n0 = blockIdx.x * 128;
  const int b = blockIdx.y;
  const unsigned short* ob = OC + (size_t)b * CH * NSP;
  const float* tb = Tn + (size_t)b * CH * NSP;

  {
    const int tn = tid >> 3;
    const int tk = tid & 7;
#pragma unroll
    for (int i = 0; i < 8; ++i) {
      const int k = 2 * tk + 16 * i;
      const uint2 ou0 = *(const uint2*)(ob + (size_t)k * NSP + n0 + 4 * tn);
      const uint2 ou1 = *(const uint2*)(ob + (size_t)(k + 1) * NSP + n0 + 4 * tn);
      const float* pt = tb + (size_t)k * NSP + n0 + 4 * tn;
      const float4 t0 = *(const float4*)pt;
      const float4 t1 = *(const float4*)(pt + NSP);
      const float z0[4] = {bflo(ou0.x) * t0.x, bfhi(ou0.x) * t0.y,
                           bflo(ou0.y) * t0.z, bfhi(ou0.y) * t0.w};
      const float z1[4] = {bflo(ou1.x) * t1.x, bfhi(ou1.x) * t1.y,
                           bflo(ou1.y) * t1.z, bfhi(ou1.y) * t1.w};
      const int kw = tk + 8 * i;
#pragma unroll
      for (int j = 0; j < 4; ++j) {
        const int nn = 4 * tn + j;
        unsigned hi, lo;
        split_pair(z0[j], z1[j], hi, lo);
        const int kws = kw ^ ((nn & 15) << 2);
        xs[nn * 64 + kws] = hi;
        xs[8192 + nn * 64 + kws] = lo;
      }
    }
  }
  __syncthreads();

  f32x4 acc[4][4];
#pragma unroll
  for (int mf = 0; mf < 4; ++mf)
#pragma unroll
    for (int nf = 0; nf < 4; ++nf) acc[mf][nf] = (f32x4){0,0,0,0};

  mfma_core(xs, w_proj, acc, tid);

  __syncthreads();
  float* bounce = (float*)xs;
  acc_to_bounce(bounce, acc, tid);
  __syncthreads();

  const int rr = tid >> 5;
  const int c4i = (tid & 31) * 4;
#pragma unroll
  for (int i = 0; i < 16; ++i) {
    const int row = rr + 8 * i;
    const float bp = b_proj[row];
    float4 v = *(const float4*)(bounce + row * 132 + c4i);
    v.x += bp; v.y += bp; v.z += bp; v.w += bp;
    *(float4*)(outp + ((size_t)b * CH + row) * NSP + n0 + c4i) = v;
  }
}

// ======================= FFT attention =======================

__device__ __forceinline__ float2 cmul(float2 a, float2 b) {
  return make_float2(fmaf(a.x, b.x, -(a.y * b.y)), fmaf(a.x, b.y, a.y * b.x));
}
#define CADD(a,b) make_float2((a).x+(b).x,(a).y+(b).y)
#define CSUB(a,b) make_float2((a).x-(b).x,(a).y-(b).y)
#define MULNI(t)  make_float2((t).y, -(t).x)
constexpr float C45 = 0.7071067811865476f;

__device__ __forceinline__ void fft8(float2* x) {
  float2 t;
  t = CSUB(x[0],x[4]); x[0]=CADD(x[0],x[4]); x[4]=t;
  t = CSUB(x[1],x[5]); x[1]=CADD(x[1],x[5]); x[5]=make_float2(C45*(t.x+t.y), C45*(t.y-t.x));
  t = CSUB(x[2],x[6]); x[2]=CADD(x[2],x[6]); x[6]=MULNI(t);
  t = CSUB(x[3],x[7]); x[3]=CADD(x[3],x[7]); x[7]=make_float2(C45*(t.y-t.x), -C45*(t.x+t.y));
  t = CSUB(x[0],x[2]); x[0]=CADD(x[0],x[2]); x[2]=t;
  t = CSUB(x[1],x[3]); x[1]=CADD(x[1],x[3]); x[3]=MULNI(t);
  t = CSUB(x[4],x[6]); x[4]=CADD(x[4],x[6]); x[6]=t;
  t = CSUB(x[5],x[7]); x[5]=CADD(x[5],x[7]); x[7]=MULNI(t);
  t = CSUB(x[0],x[1]); x[0]=CADD(x[0],x[1]); x[1]=t;
  t = CSUB(x[2],x[3]); x[2]=CADD(x[2],x[3]); x[3]=t;
  t = CSUB(x[4],x[5]); x[4]=CADD(x[4],x[5]); x[5]=t;
  t = CSUB(x[6],x[7]); x[6]=CADD(x[6],x[7]); x[7]=t;
}

__device__ __forceinline__ void fft16(float2* z) {
  float2 t;
  t=CSUB(z[0],z[8]);   z[0]=CADD(z[0],z[8]);   z[8]=t;
  t=CSUB(z[1],z[9]);   z[1]=CADD(z[1],z[9]);   z[9]=cmul(t,  make_float2( 0.9238795325f,-0.3826834324f));
  t=CSUB(z[2],z[10]);  z[2]=CADD(z[2],z[10]);  z[10]=make_float2(C45*(t.x+t.y), C45*(t.y-t.x));
  t=CSUB(z[3],z[11]);  z[3]=CADD(z[3],z[11]);  z[11]=cmul(t, make_float2( 0.3826834324f,-0.9238795325f));
  t=CSUB(z[4],z[12]);  z[4]=CADD(z[4],z[12]);  z[12]=MULNI(t);
  t=CSUB(z[5],z[13]);  z[5]=CADD(z[5],z[13]);  z[13]=cmul(t, make_float2(-0.3826834324f,-0.9238795325f));
  t=CSUB(z[6],z[14]);  z[6]=CADD(z[6],z[14]);  z[14]=make_float2(C45*(t.y-t.x), -C45*(t.x+t.y));
  t=CSUB(z[7],z[15]);  z[7]=CADD(z[7],z[15]);  z[15]=cmul(t, make_float2(-0.9238795325f,-0.3826834324f));
  t=CSUB(z[0],z[4]);   z[0]=CADD(z[0],z[4]);   z[4]=t;
  t=CSUB(z[1],z[5]);   z[1]=CADD(z[1],z[5]);   z[5]=make_float2(C45*(t.x+t.y), C45*(t.y-t.x));
  t=CSUB(z[2],z[6]);   z[2]=CADD(z[2],z[6]);   z[6]=MULNI(t);
  t=CSUB(z[3],z[7]);   z[3]=CADD(z[3],z[7]);   z[7]=make_float2(C45*(t.y-t.x), -C45*(t.x+t.y));
  t=CSUB(z[8],z[12]);  z[8]=CADD(z[8],z[12]);  z[12]=t;
  t=CSUB(z[9],z[13]);  z[9]=CADD(z[9],z[13]);  z[13]=make_float2(C45*(t.x+t.y), C45*(t.y-t.x));
  t=CSUB(z[10],z[14]); z[10]=CADD(z[10],z[14]); z[14]=MULNI(t);
  t=CSUB(z[11],z[15]); z[11]=CADD(z[11],z[15]); z[15]=make_float2(C45*(t.y-t.x), -C45*(t.x+t.y));
  t=CSUB(z[0],z[2]);   z[0]=CADD(z[0],z[2]);   z[2]=t;
  t=CSUB(z[1],z[3]);   z[1]=CADD(z[1],z[3]);   z[3]=MULNI(t);
  t=CSUB(z[4],z[6]);   z[4]=CADD(z[4],z[6]);   z[6]=t;
  t=CSUB(z[5],z[7]);   z[5]=CADD(z[5],z[7]);   z[7]=MULNI(t);
  t=CSUB(z[8],z[10]);  z[8]=CADD(z[8],z[10]);  z[10]=t;
  t=CSUB(z[9],z[11]);  z[9]=CADD(z[9],z[11]);  z[11]=MULNI(t);
  t=CSUB(z[12],z[14]); z[12]=CADD(z[12],z[14]); z[14]=t;
  t=CSUB(z[13],z[15]); z[13]=CADD(z[13],z[15]); z[15]=MULNI(t);
  t=CSUB(z[0],z[1]);   z[0]=CADD(z[0],z[1]);   z[1]=t;
  t=CSUB(z[2],z[3]);   z[2]=CADD(z[2],z[3]);   z[3]=t;
  t=CSUB(z[4],z[5]);   z[4]=CADD(z[4],z[5]);   z[5]=t;
  t=CSUB(z[6],z[7]);   z[6]=CADD(z[6],z[7]);   z[7]=t;
  t=CSUB(z[8],z[9]);   z[8]=CADD(z[8],z[9]);   z[9]=t;
  t=CSUB(z[10],z[11]); z[10]=CADD(z[10],z[11]); z[11]=t;
  t=CSUB(z[12],z[13]); z[12]=CADD(z[12],z[13]); z[13]=t;
  t=CSUB(z[14],z[15]); z[14]=CADD(z[14],z[15]); z[15]=t;
}

// SRC: 0 = LDS complex, 1 = global packed QK (z = Q + iK), 2 = LDS .x + global V bf16
// EPI: 1 = apply exp(x*escale) to .x on final write, accumulate lane-sum
template<int SPT, int SLN, int SRC, int EPI>
__device__ __forceinline__ void fft_pass(float2* img, const float2* tw,
                                         int lane, int wid,
                                         const unsigned* gqk,
                                         const unsigned short* gv,
                                         float escale, float& lsum) {
  const int n2 = lane & 15, rr = lane >> 4;
  constexpr int br3[8] = {0,4,2,6,1,5,3,7};
#pragma unroll
  for (int u = 0; u < 2; ++u) {
    const int line = wid * 8 + u * 4 + rr;
    const int lb = SLN * line;
    float2 x[8];
    if constexpr (SRC == 0) {
#pragma unroll
      for (int n1 = 0; n1 < 8; ++n1) x[n1] = img[lb + SPT * (16 * n1 + n2)];
    } else if constexpr (SRC == 1) {
#pragma unroll
      for (int n1 = 0; n1 < 8; ++n1) {
        const unsigned qk = gqk[line * 128 + 16 * n1 + n2];
        x[n1] = make_float2(bflo(qk), bfhi(qk));
      }
    } else {
#pragma unroll
      for (int n1 = 0; n1 < 8; ++n1) {
        const float a = img[lb + SPT * (16 * n1 + n2)].x;
        const unsigned short vv = gv[line * 128 + 16 * n1 + n2];
        x[n1] = make_float2(a, __uint_as_float((unsigned)vv << 16));
      }
    }
    fft8(x);
#pragma unroll
    for (int m = 0; m < 8; ++m) {
      const int k1 = br3[m];
      const float2 y = (k1 == 0) ? x[m] : cmul(x[m], tw[k1 - 1]);
      img[lb + SPT * (16 * k1 + (n2 ^ k1))] = y;
    }
  }
  const int k1 = lane & 7;
  const int lb = SLN * (wid * 8 + (lane >> 3));
  const int kb = 16 * k1;
  float2 z[16];
#pragma unroll
  for (int j = 0; j < 16; ++j) z[j] = img[lb + SPT * (kb + (j ^ k1))];
  fft16(z);
  constexpr int br4[16] = {0,8,4,12,2,10,6,14,1,9,5,13,3,11,7,15};
#pragma unroll
  for (int m = 0; m < 16; ++m) {
    const int a = lb + SPT * (k1 + 8 * br4[m]);
    if constexpr (EPI == 1) {
      const float ex = __expf(z[m].x * escale);
      lsum += ex;
      img[a] = make_float2(ex, 0.0f);
    } else {
      img[a] = z[m];
    }
  }
}

// Exact-pair cross-spectrum: Y = conj(A_f)*B_f from the packed spectrum,
// stored conj(Y) so a second forward FFT == unnormalized inverse.
__device__ __forceinline__ void cross_spectrum(float2* img, int tid) {
#pragma unroll
  for (int i = 0; i < 8; ++i) {
    const int pid = tid + (i << 10);
    int fr, fc;
    if (pid < 8064)      { fc = 1 + (pid >> 7); fr = pid & 127; }
    else if (pid < 8127) { fc = 0;  fr = pid - 8063; }
    else if (pid < 8190) { fc = 64; fr = pid - 8126; }
    else if (pid == 8190) {
#pragma unroll
      for (int s = 0; s < 4; ++s) {
        const int a = ((s >> 1) * 64) * RS + (s & 1) * 64;
        const float2 zz = img[a];
        img[a] = make_float2(zz.x * zz.y, 0.0f);
      }
      continue;
    } else continue;
    const int gr = (128 - fr) & 127, gc = 128 - fc >= 128 ? 0 : (128 - fc) & 127;
    const int f = fr * RS + fc, g = gr * RS + gc;
    const float2 zf = img[f], zg = img[g];
    const float qr = 0.5f * (zf.x + zg.x), qi = 0.5f * (zf.y - zg.y);
    const float kr = 0.5f * (zf.y + zg.y), ki = 0.5f * (zg.x - zf.x);
    const float yr = qr * kr + qi * ki;
    const float yi = qr * ki - qi * kr;
    img[f] = make_float2(yr, -yi);
    img[g] = make_float2(yr, yi);
  }
}

__global__ __launch_bounds__(NT)
void fft_attn_fused(const unsigned* __restrict__ QKin,
                    const unsigned short* __restrict__ Vin,
                    unsigned short* __restrict__ Out) {
  __shared__ float2 img[128 * RS];
  __shared__ float red[NW];
  const int tid = threadIdx.x, lane = tid & 63, wid = tid >> 6;
  const size_t off = (size_t)blockIdx.x * NSP;
  const unsigned* gqk = QKin + off;
  const unsigned short* gv = Vin + off;

  float2 tw[7];
  {
    const int n2 = lane & 15;
#pragma unroll
    for (int k = 1; k < 8; ++k) {
      float s, c;
      sincosf(6.283185307179586f * (float)(n2 * k) * (1.0f / 128.0f), &s, &c);
      tw[k - 1] = make_float2(c, -s);
    }
  }
  float dummy = 0.0f;

  // ---- stage 1: forward FFT of z = Q + iK (rows read straight from global) ----
  fft_pass<1, RS, 1, 0>(img, tw, lane, wid, gqk, nullptr, 0.0f, dummy);
  __syncthreads();
  fft_pass<RS, 1, 0, 0>(img, tw, lane, wid, nullptr, nullptr, 0.0f, dummy);
  __syncthreads();
  cross_spectrum(img, tid);
  __syncthreads();
  // inverse (conj trick) with fused exp on the final col pass
  const float escale = 1.0f / 2097152.0f;   // N^{-3/2}; |logit| O(1) -> no max-sub
  float lsum = 0.0f;
  fft_pass<1, RS, 0, 0>(img, tw, lane, wid, nullptr, nullptr, 0.0f, dummy);
  __syncthreads();
  fft_pass<RS, 1, 0, 1>(img, tw, lane, wid, nullptr, nullptr, escale, lsum);
  __syncthreads();

  // block-reduce sum of exp; normalization folds into final output scale
#pragma unroll
  for (int s = 32; s >= 1; s >>= 1) lsum += __shfl_xor(lsum, s, 64);
  if (lane == 0) red[wid] = lsum;
  __syncthreads();
  float tot = 0.0f;
#pragma unroll
  for (int w = 0; w < NW; ++w) tot += red[w];
  const float inv = 1.0f / tot;

  // ---- stage 2: forward FFT of z = exp(logit) + iV (V read from global in-pass) ----
  fft_pass<1, RS, 2, 0>(img, tw, lane, wid, nullptr, gv, 0.0f, dummy);
  __syncthreads();
  fft_pass<RS, 1, 0, 0>(img, tw, lane, wid, nullptr, nullptr, 0.0f, dummy);
  __syncthreads();
  cross_spectrum(img, tid);
  __syncthreads();
  fft_pass<1, RS, 0, 0>(img, tw, lane, wid, nullptr, nullptr, 0.0f, dummy);
  __syncthreads();
  fft_pass<RS, 1, 0, 0>(img, tw, lane, wid, nullptr, nullptr, 0.0f, dummy);
  __syncthreads();

  const float os = inv * (1.0f / 16384.0f);   // softmax 1/sum * 1/N
#pragma unroll
  for (int i = 0; i < 4; ++i) {
    const int e = (tid + i * NT) * 4;
    const float2* base = img + (e >> 7) * RS + (e & 127);
    const float4 a = *(const float4*)base;        // re0, im0, re1, im1
    const float4 c = *(const float4*)(base + 2);  // re2, im2, re3, im3
    uint2 o;
    o.x = bf16r(a.x * os) | (bf16r(a.z * os) << 16);
    o.y = bf16r(c.x * os) | (bf16r(c.z * os) << 16);
    *(uint2*)(Out + off + e) = o;
  }
}

// ---------------- launch ----------------

extern "C" void kernel_launch(void* const* d_in, const int* in_sizes, int n_in,
                              void* d_out, int out_size, void* d_ws, size_t ws_size,
                              hipStream_t stream) {
  const float* x      = (const float*)d_in[0];
  const float* w_qkv  = (const float*)d_in[1];
  const float* w_gate = (const float*)d_in[2];
  const float* b_gate = (const float*)d_in[3];
  const float* w_proj = (const float*)d_in[4];
  const float* b_proj = (const float*)d_in[5];
  float* outp = (float*)d_out;

  const size_t SZ = (size_t)BATCH * CH * NSP;   // 16,777,216 elements
  char* base = (char*)d_ws;
  unsigned*       QK = (unsigned*)base;                    // 64 MiB
  unsigned short* V  = (unsigned short*)(base + SZ * 4);   // 32 MiB
  float*          T  = (float*)(base + SZ * 6);            // 64 MiB
  unsigned short* OC = (unsigned short*)(base + SZ * 10);  // 32 MiB

  dim3 g1(128, BATCH);
  gemm_qkvg<<<g1, 256, 0, stream>>>(x, w_qkv, w_gate, b_gate, QK, V, T);

  fft_attn_fused<<<NIMG, NT, 0, stream>>>(QK, V, OC);

  dim3 g2(128, BATCH);
  gemm_proj<<<g2, 256, 0, stream>>>(OC, T, w_proj, b_proj, outp);
}